// Round 2
// baseline (13422.659 us; speedup 1.0000x reference)
//
#include <hip/hip_runtime.h>
#include <hip/hip_cooperative_groups.h>
#include <math.h>

namespace cg = cooperative_groups;

// D_MODEL=1024, N_HEADS=16, D_HEAD=64, QLEN=512, MLEN=512, KLEN=1024, BATCH=8

typedef short bf16x8 __attribute__((ext_vector_type(8)));
typedef float f32x4 __attribute__((ext_vector_type(4)));

union FragU { uint4 u; bf16x8 h; };

// split two fp32 into packed bf16-hi (truncated) and bf16-lo (exact residual, truncated)
__device__ inline void split2(float x0, float x1, unsigned& hi, unsigned& lo) {
    unsigned u0 = __float_as_uint(x0), u1 = __float_as_uint(x1);
    float h0 = __uint_as_float(u0 & 0xffff0000u);
    float h1 = __uint_as_float(u1 & 0xffff0000u);
    unsigned l0 = __float_as_uint(x0 - h0), l1 = __float_as_uint(x1 - h1);
    hi = (u0 >> 16) | (u1 & 0xffff0000u);
    lo = (l0 >> 16) | (l1 & 0xffff0000u);
}

// ---------------------------------------------------------------------------
// Weight prep: W (fp32, [n][k] if !TR else [k][n]) -> out u32[n][K] where each
// 32-k tile is 8 16B slots: {hi(k0..7),lo(k0..7),hi(k8..15),...} with slot
// index XOR (n&7)  (pre-swizzled global so GEMM LDS staging is a linear copy).
// ---------------------------------------------------------------------------
template<bool TR>
__global__ __launch_bounds__(256) void prep_w(
    const float* __restrict__ W, unsigned* __restrict__ out, int Nr, int K, int ldw)
{
    int idx = blockIdx.x * 256 + threadIdx.x;
    int cpr = K >> 3;
    if (idx >= Nr * cpr) return;
    int n, c;
    if (TR) { n = idx % Nr; c = idx / Nr; }         // coalesced strided reads
    else    { c = idx % cpr; n = idx / cpr; }       // coalesced row reads
    int kt = c >> 2, j = c & 3;
    int k = kt * 32 + j * 8;
    float x[8];
    #pragma unroll
    for (int i = 0; i < 8; ++i)
        x[i] = TR ? W[(size_t)(k + i) * ldw + n] : W[(size_t)n * ldw + k + i];
    unsigned h[4], l[4];
    split2(x[0], x[1], h[0], l[0]);
    split2(x[2], x[3], h[1], l[1]);
    split2(x[4], x[5], h[2], l[2]);
    split2(x[6], x[7], h[3], l[3]);
    unsigned* base = out + (size_t)n * K + kt * 32;
    *(uint4*)(base + (((2 * j) ^ (n & 7)) * 4))     = make_uint4(h[0], h[1], h[2], h[3]);
    *(uint4*)(base + (((2 * j + 1) ^ (n & 7)) * 4)) = make_uint4(l[0], l[1], l[2], l[3]);
}

// ---------------------------------------------------------------------------
// Split-bf16 MFMA GEMM: C[m,n] = sum_k A[m,k]*B[k,n] (+bias), fp32 I/O.
// A fp32 (converted+swizzled during staging), B pre-prepped u32[n][K].
// 128x128 tile, BK=32, 256 threads (4 waves, 2x2 of 64x64), 16x16x32 bf16 MFMA,
// 3 MFMA per fragment pair (hi*hi + hi*lo + lo*hi).
// AMODE: 0 plain A; 1 cat gather (row<4096 -> A, else A2 at row-4096).
// ---------------------------------------------------------------------------
template<int AMODE, bool BIAS>
__global__ __launch_bounds__(256) void gemm_mfma(
    const float* __restrict__ A, const float* __restrict__ A2,
    const unsigned* __restrict__ Bp, const float* __restrict__ bias,
    float* __restrict__ C, int M, int N, int K, int lda, int ldc)
{
    __shared__ uint4 Ab[1024];   // [row][8 slots] 16KB
    __shared__ uint4 Bb[1024];
    int tid = threadIdx.x;
    int lane = tid & 63, wid = tid >> 6;
    int wr = wid >> 1, wc = wid & 1;
    int n0 = blockIdx.x * 128, m0 = blockIdx.y * 128;
    int r15 = lane & 15, s = lane >> 4;

    f32x4 acc[4][4];
    #pragma unroll
    for (int i = 0; i < 4; ++i)
        #pragma unroll
        for (int j = 0; j < 4; ++j) acc[i][j] = 0.0f;

    for (int kt = 0; kt < (K >> 5); ++kt) {
        int k0 = kt * 32;
        // ---- stage A (convert fp32 -> hi/lo bf16, swizzled slots)
        #pragma unroll
        for (int q = 0; q < 2; ++q) {
            int idx = q * 256 + tid;
            int row = idx >> 2, j = idx & 3;
            const float* ap;
            if (AMODE == 1) {
                int gm = m0 + row;
                ap = (gm < 4096) ? (A + (size_t)gm * lda) : (A2 + (size_t)(gm - 4096) * lda);
            } else {
                ap = A + (size_t)(m0 + row) * lda;
            }
            float4 x0 = *(const float4*)(ap + k0 + j * 8);
            float4 x1 = *(const float4*)(ap + k0 + j * 8 + 4);
            unsigned h[4], l[4];
            split2(x0.x, x0.y, h[0], l[0]);
            split2(x0.z, x0.w, h[1], l[1]);
            split2(x1.x, x1.y, h[2], l[2]);
            split2(x1.z, x1.w, h[3], l[3]);
            Ab[row * 8 + (((2 * j) ^ (row & 7)))]     = make_uint4(h[0], h[1], h[2], h[3]);
            Ab[row * 8 + (((2 * j + 1) ^ (row & 7)))] = make_uint4(l[0], l[1], l[2], l[3]);
        }
        // ---- stage B (linear copy of pre-swizzled global)
        #pragma unroll
        for (int q = 0; q < 4; ++q) {
            int idx = q * 256 + tid;
            int row = idx >> 3, slot = idx & 7;
            Bb[idx] = *(const uint4*)(Bp + (size_t)(n0 + row) * K + k0 + slot * 4);
        }
        __syncthreads();
        // ---- fragments + MFMA
        FragU ahi[4], alo[4], bhi[4], blo[4];
        #pragma unroll
        for (int f = 0; f < 4; ++f) {
            int ar = wr * 64 + f * 16 + r15;
            ahi[f].u = Ab[ar * 8 + ((2 * s) ^ (ar & 7))];
            alo[f].u = Ab[ar * 8 + ((2 * s + 1) ^ (ar & 7))];
            int br = wc * 64 + f * 16 + r15;
            bhi[f].u = Bb[br * 8 + ((2 * s) ^ (br & 7))];
            blo[f].u = Bb[br * 8 + ((2 * s + 1) ^ (br & 7))];
        }
        #pragma unroll
        for (int fi = 0; fi < 4; ++fi)
            #pragma unroll
            for (int fj = 0; fj < 4; ++fj) {
                acc[fi][fj] = __builtin_amdgcn_mfma_f32_16x16x32_bf16(ahi[fi].h, bhi[fj].h, acc[fi][fj], 0, 0, 0);
                acc[fi][fj] = __builtin_amdgcn_mfma_f32_16x16x32_bf16(ahi[fi].h, blo[fj].h, acc[fi][fj], 0, 0, 0);
                acc[fi][fj] = __builtin_amdgcn_mfma_f32_16x16x32_bf16(alo[fi].h, bhi[fj].h, acc[fi][fj], 0, 0, 0);
            }
        __syncthreads();
    }
    // ---- epilogue: C/D layout col=lane&15, row=(lane>>4)*4+reg
    int r4 = (lane >> 4) * 4;
    #pragma unroll
    for (int fj = 0; fj < 4; ++fj) {
        int n = n0 + wc * 64 + fj * 16 + r15;
        float bv = BIAS ? bias[n] : 0.f;
        #pragma unroll
        for (int fi = 0; fi < 4; ++fi) {
            int m = m0 + wr * 64 + fi * 16 + r4;
            #pragma unroll
            for (int r = 0; r < 4; ++r)
                C[(size_t)(m + r) * ldc + n] = acc[fi][fj][r] + bv;
        }
    }
}

// ---------------------------------------------------------------------------
// Fused TXL attention (unchanged from round 0, fp32).
// ---------------------------------------------------------------------------
__global__ __launch_bounds__(256) void attn_fused(
    const float* __restrict__ qkv, const float* __restrict__ rk,
    const float* __restrict__ u_, const float* __restrict__ v_,
    float* __restrict__ y1)
{
    __shared__ float qu[64][68], qv[64][68], Kt[64][68], Vt[64][68];
    __shared__ float RKs[128][68];
    __shared__ float S[64][68];
    __shared__ float mrow[64], lrow[64], scalef[64];
    __shared__ float pmax[64][16], psum[64][16];

    int tid = threadIdx.x;
    int it = blockIdx.x, b = blockIdx.y, h = blockIdx.z;
    int i0 = it * 64;
    int ti = tid >> 4, tj = tid & 15;

    {
        int r = tid >> 2, c0 = (tid & 3) * 16;
        size_t base = ((size_t)(i0 + r + 512) * 8 + b) * 3072 + h * 64;
        #pragma unroll
        for (int q = 0; q < 4; ++q) {
            int c = c0 + q * 4;
            float4 qq = *(const float4*)&qkv[base + c];
            float4 uu = *(const float4*)&u_[h * 64 + c];
            float4 vv = *(const float4*)&v_[h * 64 + c];
            *(float4*)&qu[r][c] = make_float4(qq.x + uu.x, qq.y + uu.y, qq.z + uu.z, qq.w + uu.w);
            *(float4*)&qv[r][c] = make_float4(qq.x + vv.x, qq.y + vv.y, qq.z + vv.z, qq.w + vv.w);
        }
    }
    if (tid < 64) { mrow[tid] = -1e30f; lrow[tid] = 0.f; }

    float Od[4][4] = {};
    int njt = it + 9;

    for (int jt = 0; jt < njt; ++jt) {
        int j0 = jt * 64;
        __syncthreads();
        {
            int r = tid >> 2, c0 = (tid & 3) * 16;
            size_t kb = ((size_t)(j0 + r) * 8 + b) * 3072 + 1024 + h * 64;
            #pragma unroll
            for (int q = 0; q < 4; ++q) {
                int c = c0 + q * 4;
                *(float4*)&Kt[r][c] = *(const float4*)&qkv[kb + c];
                *(float4*)&Vt[r][c] = *(const float4*)&qkv[kb + 1024 + c];
            }
        }
        {
            int r2 = tid >> 1, c0 = (tid & 1) * 32;
            int jj = j0 - i0 + 448 + r2;
            jj = jj < 0 ? 0 : (jj > 1023 ? 1023 : jj);
            size_t rb = (size_t)jj * 1024 + h * 64;
            #pragma unroll
            for (int q = 0; q < 8; ++q) {
                int c = c0 + q * 4;
                *(float4*)&RKs[r2][c] = *(const float4*)&rk[rb + c];
            }
        }
        __syncthreads();

        float acc[4][4] = {};
        int jlb = (tj - ti) * 4 + 60;
        #pragma unroll 4
        for (int d4 = 0; d4 < 64; d4 += 4) {
            float4 Aq[4], Cq[4], Kv[4], Rv[7];
            #pragma unroll
            for (int i = 0; i < 4; ++i) {
                Aq[i] = *(float4*)&qu[ti * 4 + i][d4];
                Cq[i] = *(float4*)&qv[ti * 4 + i][d4];
                Kv[i] = *(float4*)&Kt[tj * 4 + i][d4];
            }
            #pragma unroll
            for (int t = 0; t < 7; ++t)
                Rv[t] = *(float4*)&RKs[jlb + t][d4];
            #pragma unroll
            for (int i = 0; i < 4; ++i)
                #pragma unroll
                for (int j = 0; j < 4; ++j) {
                    float4 kk = Kv[j];
                    float4 rr = Rv[j - i + 3];
                    acc[i][j] += Aq[i].x * kk.x + Aq[i].y * kk.y + Aq[i].z * kk.z + Aq[i].w * kk.w
                               + Cq[i].x * rr.x + Cq[i].y * rr.y + Cq[i].z * rr.z + Cq[i].w * rr.w;
                }
        }
        #pragma unroll
        for (int i = 0; i < 4; ++i) {
            int gi = i0 + ti * 4 + i;
            float mx = -1e30f;
            #pragma unroll
            for (int j = 0; j < 4; ++j) {
                int gj = j0 + tj * 4 + j;
                float vS = acc[i][j] * 0.125f;
                if (gj > gi + 512) vS = -1e30f;
                acc[i][j] = vS;
                mx = fmaxf(mx, vS);
            }
            pmax[ti * 4 + i][tj] = mx;
        }
        __syncthreads();
        if (tid < 64) {
            float mo = mrow[tid], mn = mo;
            #pragma unroll
            for (int t = 0; t < 16; ++t) mn = fmaxf(mn, pmax[tid][t]);
            mrow[tid] = mn;
            scalef[tid] = __expf(mo - mn);
        }
        __syncthreads();
        #pragma unroll
        for (int i = 0; i < 4; ++i) {
            int ri = ti * 4 + i;
            float mn = mrow[ri];
            float4 pv;
            pv.x = __expf(acc[i][0] - mn);
            pv.y = __expf(acc[i][1] - mn);
            pv.z = __expf(acc[i][2] - mn);
            pv.w = __expf(acc[i][3] - mn);
            *(float4*)&S[ri][tj * 4] = pv;
            psum[ri][tj] = pv.x + pv.y + pv.z + pv.w;
            float scl = scalef[ri];
            #pragma unroll
            for (int j2 = 0; j2 < 4; ++j2) Od[i][j2] *= scl;
        }
        __syncthreads();
        if (tid < 64) {
            float s = 0.f;
            #pragma unroll
            for (int t = 0; t < 16; ++t) s += psum[tid][t];
            lrow[tid] = lrow[tid] * scalef[tid] + s;
        }
        #pragma unroll 4
        for (int jb = 0; jb < 64; jb += 4) {
            float4 p0 = *(float4*)&S[ti * 4 + 0][jb];
            float4 p1 = *(float4*)&S[ti * 4 + 1][jb];
            float4 p2 = *(float4*)&S[ti * 4 + 2][jb];
            float4 p3 = *(float4*)&S[ti * 4 + 3][jb];
            float4 v0 = *(float4*)&Vt[jb + 0][tj * 4];
            float4 v1 = *(float4*)&Vt[jb + 1][tj * 4];
            float4 v2 = *(float4*)&Vt[jb + 2][tj * 4];
            float4 v3 = *(float4*)&Vt[jb + 3][tj * 4];
            float4 pr[4] = {p0, p1, p2, p3};
            #pragma unroll
            for (int i = 0; i < 4; ++i) {
                Od[i][0] += pr[i].x * v0.x + pr[i].y * v1.x + pr[i].z * v2.x + pr[i].w * v3.x;
                Od[i][1] += pr[i].x * v0.y + pr[i].y * v1.y + pr[i].z * v2.y + pr[i].w * v3.y;
                Od[i][2] += pr[i].x * v0.z + pr[i].y * v1.z + pr[i].z * v2.z + pr[i].w * v3.z;
                Od[i][3] += pr[i].x * v0.w + pr[i].y * v1.w + pr[i].z * v2.w + pr[i].w * v3.w;
            }
        }
    }
    __syncthreads();
    #pragma unroll
    for (int i = 0; i < 4; ++i) {
        int ri = ti * 4 + i;
        float inv = 1.f / lrow[ri];
        float4 o = make_float4(Od[i][0] * inv, Od[i][1] * inv, Od[i][2] * inv, Od[i][3] * inv);
        *(float4*)&y1[((size_t)(i0 + ri) * 8 + b) * 1024 + h * 64 + tj * 4] = o;
    }
}

// ---------------------------------------------------------------------------
// Persistent GRU: 128 blocks x 512 threads, cooperative (grid.sync per step).
// Wave w owns output dim d = blockIdx*8 + w; Whh rows (r,z,n) for d held in
// registers (48 floats/lane, lane covers k in [lane*16, lane*16+16)).
// ---------------------------------------------------------------------------
__global__ __launch_bounds__(512) void gru_persistent(
    const float* __restrict__ h0, float* __restrict__ hA, float* __restrict__ hB,
    const float* __restrict__ Whh, const float* __restrict__ bhh,
    const float* __restrict__ xg, float* __restrict__ out)
{
    cg::grid_group grid = cg::this_grid();
    int lane = threadIdx.x & 63;
    int wave = threadIdx.x >> 6;
    int d = blockIdx.x * 8 + wave;
    int kb = lane << 4;

    float4 wgt[3][4];
    #pragma unroll
    for (int g = 0; g < 3; ++g)
        #pragma unroll
        for (int q = 0; q < 4; ++q)
            wgt[g][q] = *(const float4*)&Whh[(size_t)(g * 1024 + d) * 1024 + kb + q * 4];
    float b_r = bhh[d], b_z = bhh[1024 + d], b_n = bhh[2048 + d];

    for (int t = 0; t < 512; ++t) {
        const float* hi_ = (t == 0) ? h0 : ((t & 1) ? hA : hB);
        float* ho = (t & 1) ? hB : hA;

        // early loads (independent of the dot products)
        float xr = 0.f, xz = 0.f, xn = 0.f, hprev = 0.f;
        if (lane < 8) {
            size_t xb = ((size_t)t * 8 + lane) * 3072 + d;
            xr = xg[xb];
            xz = xg[xb + 1024];
            xn = xg[xb + 2048];
            hprev = hi_[lane * 1024 + d];
        }

        float acc[3][8];
        #pragma unroll
        for (int g = 0; g < 3; ++g)
            #pragma unroll
            for (int b = 0; b < 8; ++b) acc[g][b] = 0.f;

        #pragma unroll
        for (int b = 0; b < 8; ++b) {
            const float* hb = hi_ + b * 1024 + kb;
            float4 h0v = *(const float4*)(hb);
            float4 h1v = *(const float4*)(hb + 4);
            float4 h2v = *(const float4*)(hb + 8);
            float4 h3v = *(const float4*)(hb + 12);
            #pragma unroll
            for (int g = 0; g < 3; ++g) {
                acc[g][b] += wgt[g][0].x * h0v.x + wgt[g][0].y * h0v.y + wgt[g][0].z * h0v.z + wgt[g][0].w * h0v.w
                           + wgt[g][1].x * h1v.x + wgt[g][1].y * h1v.y + wgt[g][1].z * h1v.z + wgt[g][1].w * h1v.w
                           + wgt[g][2].x * h2v.x + wgt[g][2].y * h2v.y + wgt[g][2].z * h2v.z + wgt[g][2].w * h2v.w
                           + wgt[g][3].x * h3v.x + wgt[g][3].y * h3v.y + wgt[g][3].z * h3v.z + wgt[g][3].w * h3v.w;
            }
        }
        // butterfly reduce each (g,b) over 64 lanes
        #pragma unroll
        for (int g = 0; g < 3; ++g)
            #pragma unroll
            for (int b = 0; b < 8; ++b) {
                float v = acc[g][b];
                v += __shfl_xor(v, 32);
                v += __shfl_xor(v, 16);
                v += __shfl_xor(v, 8);
                v += __shfl_xor(v, 4);
                v += __shfl_xor(v, 2);
                v += __shfl_xor(v, 1);
                acc[g][b] = v;
            }

        if (lane < 8) {
            float s0 = acc[0][0], s1 = acc[1][0], s2 = acc[2][0];
            #pragma unroll
            for (int b = 1; b < 8; ++b)
                if (lane == b) { s0 = acc[0][b]; s1 = acc[1][b]; s2 = acc[2][b]; }
            float rr = 1.f / (1.f + __expf(-(xr + s0 + b_r)));
            float zz = 1.f / (1.f + __expf(-(xz + s1 + b_z)));
            float nn = tanhf(xn + rr * (s2 + b_n));
            float hn = (1.f - zz) * nn + zz * hprev;
            ho[lane * 1024 + d] = hn;
            out[((size_t)t * 8 + lane) * 1024 + d] = hn;
        }
        if (t != 511) grid.sync();
    }
}

// ---------------------------------------------------------------------------
// Fallback GRU step (round-0 kernel) if cooperative launch is unavailable.
// ---------------------------------------------------------------------------
__global__ __launch_bounds__(256) void gru_step(
    const float* __restrict__ hin, float* __restrict__ hout,
    const float* __restrict__ Whh, const float* __restrict__ bhh,
    const float* __restrict__ xg, float* __restrict__ out, int step)
{
    __shared__ float hs[8192];
    __shared__ float red[24][256];
    int tid = threadIdx.x;
    int w = blockIdx.x;

    #pragma unroll
    for (int q = 0; q < 8; ++q) {
        int i4 = q * 256 + tid;
        *(float4*)&hs[i4 * 4] = *(const float4*)&hin[i4 * 4];
    }
    __syncthreads();

    int dd = tid & 15, kc = tid >> 4;
    int d = w * 16 + dd;
    float acc0[8] = {}, acc1[8] = {}, acc2[8] = {};
    const float* w0 = Whh + (size_t)d * 1024 + kc * 64;
    const float* w1 = Whh + (size_t)(1024 + d) * 1024 + kc * 64;
    const float* w2 = Whh + (size_t)(2048 + d) * 1024 + kc * 64;
    #pragma unroll 4
    for (int k4 = 0; k4 < 64; k4 += 4) {
        float4 wr = *(const float4*)(w0 + k4);
        float4 wz = *(const float4*)(w1 + k4);
        float4 wn = *(const float4*)(w2 + k4);
        int kbase = kc * 64 + k4;
        #pragma unroll
        for (int b = 0; b < 8; ++b) {
            float4 h4 = *(const float4*)&hs[b * 1024 + kbase];
            acc0[b] += wr.x * h4.x + wr.y * h4.y + wr.z * h4.z + wr.w * h4.w;
            acc1[b] += wz.x * h4.x + wz.y * h4.y + wz.z * h4.z + wz.w * h4.w;
            acc2[b] += wn.x * h4.x + wn.y * h4.y + wn.z * h4.z + wn.w * h4.w;
        }
    }
    int c = kc * 16 + dd;
    #pragma unroll
    for (int b = 0; b < 8; ++b) {
        red[b][c]      = acc0[b];
        red[8 + b][c]  = acc1[b];
        red[16 + b][c] = acc2[b];
    }
    __syncthreads();

    if (tid < 128) {
        int b = tid >> 4, d2l = tid & 15;
        int d2 = w * 16 + d2l;
        float s0 = 0.f, s1 = 0.f, s2 = 0.f;
        #pragma unroll
        for (int k2 = 0; k2 < 16; ++k2) {
            s0 += red[b][k2 * 16 + d2l];
            s1 += red[8 + b][k2 * 16 + d2l];
            s2 += red[16 + b][k2 * 16 + d2l];
        }
        size_t xb = ((size_t)step * 8 + b) * 3072;
        float xr = xg[xb + d2];
        float xz = xg[xb + 1024 + d2];
        float xn = xg[xb + 2048 + d2];
        float r = 1.f / (1.f + __expf(-(xr + s0 + bhh[d2])));
        float z = 1.f / (1.f + __expf(-(xz + s1 + bhh[1024 + d2])));
        float n = tanhf(xn + r * (s2 + bhh[2048 + d2]));
        float hprev = hs[b * 1024 + d2];
        float hnew = (1.f - z) * n + z * hprev;
        hout[b * 1024 + d2] = hnew;
        out[((size_t)step * 8 + b) * 1024 + d2] = hnew;
    }
}

// ---------------------------------------------------------------------------
extern "C" void kernel_launch(void* const* d_in, const int* in_sizes, int n_in,
                              void* d_out, int out_size, void* d_ws, size_t ws_size,
                              hipStream_t stream) {
    (void)in_sizes; (void)n_in; (void)out_size; (void)ws_size;
    const float* inputs = (const float*)d_in[0];
    const float* r_in   = (const float*)d_in[1];
    const float* u_in   = (const float*)d_in[2];
    const float* v_in   = (const float*)d_in[3];
    const float* mem    = (const float*)d_in[4];
    const float* Wqkv   = (const float*)d_in[5];
    const float* Wr     = (const float*)d_in[6];
    const float* Wo     = (const float*)d_in[7];
    const float* Wih    = (const float*)d_in[8];
    const float* Whh    = (const float*)d_in[9];
    const float* bih    = (const float*)d_in[10];
    const float* bhh    = (const float*)d_in[11];
    const float* h0     = (const float*)d_in[12];
    float* out = (float*)d_out;
    float* ws = (float*)d_ws;

    float*    qkv   = ws;                       // 25165824
    float*    rk    = ws + 25165824;            //  1048576
    float*    y1    = ws + 26214400;            //  4194304
    float*    y2    = ws + 30408704;            //  4194304
    float*    xg    = ws + 34603008;            // 12582912
    float*    hA    = ws + 47185920;            //     8192
    float*    hB    = ws + 47194112;            //     8192
    unsigned* WqkvP = (unsigned*)(ws + 47202304);   // 3145728
    unsigned* WrP   = (unsigned*)(ws + 50348032);   // 1048576
    unsigned* WoP   = (unsigned*)(ws + 51396608);   // 1048576
    unsigned* WihP  = (unsigned*)(ws + 52445184);   // 3145728

    dim3 blk(256);
    // ---- weight prep (bf16 hi/lo split, pre-swizzled [n][k])
    prep_w<true ><<<1536, blk, 0, stream>>>(Wqkv, WqkvP, 3072, 1024, 3072);
    prep_w<true ><<< 512, blk, 0, stream>>>(Wr,   WrP,   1024, 1024, 1024);
    prep_w<true ><<< 512, blk, 0, stream>>>(Wo,   WoP,   1024, 1024, 1024);
    prep_w<false><<<1536, blk, 0, stream>>>(Wih,  WihP,  3072, 1024, 1024);

    // ---- qkv = [mem; inputs] @ W_qkv   (8192 x 3072, K=1024)
    gemm_mfma<1, false><<<dim3(24, 64), blk, 0, stream>>>(
        mem, inputs, WqkvP, nullptr, qkv, 8192, 3072, 1024, 1024, 3072);
    // ---- rk = r @ W_r                  (1024 x 1024)
    gemm_mfma<0, false><<<dim3(8, 8), blk, 0, stream>>>(
        r_in, nullptr, WrP, nullptr, rk, 1024, 1024, 1024, 1024, 1024);
    // ---- fused attention -> y1
    attn_fused<<<dim3(8, 8, 16), blk, 0, stream>>>(qkv, rk, u_in, v_in, y1);
    // ---- y2 = y1 @ W_o                 (4096 x 1024)
    gemm_mfma<0, false><<<dim3(8, 32), blk, 0, stream>>>(
        y1, nullptr, WoP, nullptr, y2, 4096, 1024, 1024, 1024, 1024);
    // ---- xg = y2 @ W_ih^T + b_ih       (4096 x 3072)
    gemm_mfma<0, true><<<dim3(24, 32), blk, 0, stream>>>(
        y2, nullptr, WihP, bih, xg, 4096, 3072, 1024, 1024, 3072);

    // ---- GRU recurrence: persistent cooperative kernel (fallback: 512 launches)
    {
        const float* a0 = h0; float* a1 = hA; float* a2 = hB;
        const float* a3 = Whh; const float* a4 = bhh; const float* a5 = xg;
        float* a6 = out;
        void* args[7] = {&a0, &a1, &a2, &a3, &a4, &a5, &a6};
        hipError_t e = hipLaunchCooperativeKernel((void*)gru_persistent,
                                                  dim3(128), dim3(512), args, 0, stream);
        if (e != hipSuccess) {
            const float* hin = h0;
            for (int s = 0; s < 512; ++s) {
                float* hp = (s & 1) ? hB : hA;
                gru_step<<<64, blk, 0, stream>>>(hin, hp, Whh, bhh, xg, out, s);
                hin = hp;
            }
        }
    }
}

// Round 3
// 12169.550 us; speedup vs baseline: 1.1030x; 1.1030x over previous
//
#include <hip/hip_runtime.h>
#include <hip/hip_cooperative_groups.h>
#include <math.h>

namespace cg = cooperative_groups;

// D_MODEL=1024, N_HEADS=16, D_HEAD=64, QLEN=512, MLEN=512, KLEN=1024, BATCH=8

typedef short bf16x8 __attribute__((ext_vector_type(8)));
typedef float f32x4 __attribute__((ext_vector_type(4)));

union FragU { uint4 u; bf16x8 h; };

// split two fp32 into packed bf16-hi (truncated) and bf16-lo (exact residual, truncated)
__device__ inline void split2(float x0, float x1, unsigned& hi, unsigned& lo) {
    unsigned u0 = __float_as_uint(x0), u1 = __float_as_uint(x1);
    float h0 = __uint_as_float(u0 & 0xffff0000u);
    float h1 = __uint_as_float(u1 & 0xffff0000u);
    unsigned l0 = __float_as_uint(x0 - h0), l1 = __float_as_uint(x1 - h1);
    hi = (u0 >> 16) | (u1 & 0xffff0000u);
    lo = (l0 >> 16) | (l1 & 0xffff0000u);
}

// ---------------------------------------------------------------------------
// Weight prep: W (fp32, [n][k] if !TR else [k][n]) -> out u32[n][K] where each
// 32-k tile is 8 16B slots: {hi(k0..7),lo(k0..7),hi(k8..15),...} with slot
// index XOR (n&7)  (pre-swizzled global so GEMM LDS staging is a linear copy).
// ---------------------------------------------------------------------------
template<bool TR>
__global__ __launch_bounds__(256) void prep_w(
    const float* __restrict__ W, unsigned* __restrict__ out, int Nr, int K, int ldw)
{
    int idx = blockIdx.x * 256 + threadIdx.x;
    int cpr = K >> 3;
    if (idx >= Nr * cpr) return;
    int n, c;
    if (TR) { n = idx % Nr; c = idx / Nr; }         // coalesced strided reads
    else    { c = idx % cpr; n = idx / cpr; }       // coalesced row reads
    int kt = c >> 2, j = c & 3;
    int k = kt * 32 + j * 8;
    float x[8];
    #pragma unroll
    for (int i = 0; i < 8; ++i)
        x[i] = TR ? W[(size_t)(k + i) * ldw + n] : W[(size_t)n * ldw + k + i];
    unsigned h[4], l[4];
    split2(x[0], x[1], h[0], l[0]);
    split2(x[2], x[3], h[1], l[1]);
    split2(x[4], x[5], h[2], l[2]);
    split2(x[6], x[7], h[3], l[3]);
    unsigned* base = out + (size_t)n * K + kt * 32;
    *(uint4*)(base + (((2 * j) ^ (n & 7)) * 4))     = make_uint4(h[0], h[1], h[2], h[3]);
    *(uint4*)(base + (((2 * j + 1) ^ (n & 7)) * 4)) = make_uint4(l[0], l[1], l[2], l[3]);
}

// ---------------------------------------------------------------------------
// Split-bf16 MFMA GEMM (unchanged from round 2).
// ---------------------------------------------------------------------------
template<int AMODE, bool BIAS>
__global__ __launch_bounds__(256) void gemm_mfma(
    const float* __restrict__ A, const float* __restrict__ A2,
    const unsigned* __restrict__ Bp, const float* __restrict__ bias,
    float* __restrict__ C, int M, int N, int K, int lda, int ldc)
{
    __shared__ uint4 Ab[1024];   // [row][8 slots] 16KB
    __shared__ uint4 Bb[1024];
    int tid = threadIdx.x;
    int lane = tid & 63, wid = tid >> 6;
    int wr = wid >> 1, wc = wid & 1;
    int n0 = blockIdx.x * 128, m0 = blockIdx.y * 128;
    int r15 = lane & 15, s = lane >> 4;

    f32x4 acc[4][4];
    #pragma unroll
    for (int i = 0; i < 4; ++i)
        #pragma unroll
        for (int j = 0; j < 4; ++j) acc[i][j] = 0.0f;

    for (int kt = 0; kt < (K >> 5); ++kt) {
        int k0 = kt * 32;
        // ---- stage A (convert fp32 -> hi/lo bf16, swizzled slots)
        #pragma unroll
        for (int q = 0; q < 2; ++q) {
            int idx = q * 256 + tid;
            int row = idx >> 2, j = idx & 3;
            const float* ap;
            if (AMODE == 1) {
                int gm = m0 + row;
                ap = (gm < 4096) ? (A + (size_t)gm * lda) : (A2 + (size_t)(gm - 4096) * lda);
            } else {
                ap = A + (size_t)(m0 + row) * lda;
            }
            float4 x0 = *(const float4*)(ap + k0 + j * 8);
            float4 x1 = *(const float4*)(ap + k0 + j * 8 + 4);
            unsigned h[4], l[4];
            split2(x0.x, x0.y, h[0], l[0]);
            split2(x0.z, x0.w, h[1], l[1]);
            split2(x1.x, x1.y, h[2], l[2]);
            split2(x1.z, x1.w, h[3], l[3]);
            Ab[row * 8 + (((2 * j) ^ (row & 7)))]     = make_uint4(h[0], h[1], h[2], h[3]);
            Ab[row * 8 + (((2 * j + 1) ^ (row & 7)))] = make_uint4(l[0], l[1], l[2], l[3]);
        }
        // ---- stage B (linear copy of pre-swizzled global)
        #pragma unroll
        for (int q = 0; q < 4; ++q) {
            int idx = q * 256 + tid;
            int row = idx >> 3, slot = idx & 7;
            Bb[idx] = *(const uint4*)(Bp + (size_t)(n0 + row) * K + k0 + slot * 4);
        }
        __syncthreads();
        // ---- fragments + MFMA
        FragU ahi[4], alo[4], bhi[4], blo[4];
        #pragma unroll
        for (int f = 0; f < 4; ++f) {
            int ar = wr * 64 + f * 16 + r15;
            ahi[f].u = Ab[ar * 8 + ((2 * s) ^ (ar & 7))];
            alo[f].u = Ab[ar * 8 + ((2 * s + 1) ^ (ar & 7))];
            int br = wc * 64 + f * 16 + r15;
            bhi[f].u = Bb[br * 8 + ((2 * s) ^ (br & 7))];
            blo[f].u = Bb[br * 8 + ((2 * s + 1) ^ (br & 7))];
        }
        #pragma unroll
        for (int fi = 0; fi < 4; ++fi)
            #pragma unroll
            for (int fj = 0; fj < 4; ++fj) {
                acc[fi][fj] = __builtin_amdgcn_mfma_f32_16x16x32_bf16(ahi[fi].h, bhi[fj].h, acc[fi][fj], 0, 0, 0);
                acc[fi][fj] = __builtin_amdgcn_mfma_f32_16x16x32_bf16(ahi[fi].h, blo[fj].h, acc[fi][fj], 0, 0, 0);
                acc[fi][fj] = __builtin_amdgcn_mfma_f32_16x16x32_bf16(alo[fi].h, bhi[fj].h, acc[fi][fj], 0, 0, 0);
            }
        __syncthreads();
    }
    // ---- epilogue: C/D layout col=lane&15, row=(lane>>4)*4+reg
    int r4 = (lane >> 4) * 4;
    #pragma unroll
    for (int fj = 0; fj < 4; ++fj) {
        int n = n0 + wc * 64 + fj * 16 + r15;
        float bv = BIAS ? bias[n] : 0.f;
        #pragma unroll
        for (int fi = 0; fi < 4; ++fi) {
            int m = m0 + wr * 64 + fi * 16 + r4;
            #pragma unroll
            for (int r = 0; r < 4; ++r)
                C[(size_t)(m + r) * ldc + n] = acc[fi][fj][r] + bv;
        }
    }
}

// ---------------------------------------------------------------------------
// Fused TXL attention (unchanged, fp32).
// ---------------------------------------------------------------------------
__global__ __launch_bounds__(256) void attn_fused(
    const float* __restrict__ qkv, const float* __restrict__ rk,
    const float* __restrict__ u_, const float* __restrict__ v_,
    float* __restrict__ y1)
{
    __shared__ float qu[64][68], qv[64][68], Kt[64][68], Vt[64][68];
    __shared__ float RKs[128][68];
    __shared__ float S[64][68];
    __shared__ float mrow[64], lrow[64], scalef[64];
    __shared__ float pmax[64][16], psum[64][16];

    int tid = threadIdx.x;
    int it = blockIdx.x, b = blockIdx.y, h = blockIdx.z;
    int i0 = it * 64;
    int ti = tid >> 4, tj = tid & 15;

    {
        int r = tid >> 2, c0 = (tid & 3) * 16;
        size_t base = ((size_t)(i0 + r + 512) * 8 + b) * 3072 + h * 64;
        #pragma unroll
        for (int q = 0; q < 4; ++q) {
            int c = c0 + q * 4;
            float4 qq = *(const float4*)&qkv[base + c];
            float4 uu = *(const float4*)&u_[h * 64 + c];
            float4 vv = *(const float4*)&v_[h * 64 + c];
            *(float4*)&qu[r][c] = make_float4(qq.x + uu.x, qq.y + uu.y, qq.z + uu.z, qq.w + uu.w);
            *(float4*)&qv[r][c] = make_float4(qq.x + vv.x, qq.y + vv.y, qq.z + vv.z, qq.w + vv.w);
        }
    }
    if (tid < 64) { mrow[tid] = -1e30f; lrow[tid] = 0.f; }

    float Od[4][4] = {};
    int njt = it + 9;

    for (int jt = 0; jt < njt; ++jt) {
        int j0 = jt * 64;
        __syncthreads();
        {
            int r = tid >> 2, c0 = (tid & 3) * 16;
            size_t kb = ((size_t)(j0 + r) * 8 + b) * 3072 + 1024 + h * 64;
            #pragma unroll
            for (int q = 0; q < 4; ++q) {
                int c = c0 + q * 4;
                *(float4*)&Kt[r][c] = *(const float4*)&qkv[kb + c];
                *(float4*)&Vt[r][c] = *(const float4*)&qkv[kb + 1024 + c];
            }
        }
        {
            int r2 = tid >> 1, c0 = (tid & 1) * 32;
            int jj = j0 - i0 + 448 + r2;
            jj = jj < 0 ? 0 : (jj > 1023 ? 1023 : jj);
            size_t rb = (size_t)jj * 1024 + h * 64;
            #pragma unroll
            for (int q = 0; q < 8; ++q) {
                int c = c0 + q * 4;
                *(float4*)&RKs[r2][c] = *(const float4*)&rk[rb + c];
            }
        }
        __syncthreads();

        float acc[4][4] = {};
        int jlb = (tj - ti) * 4 + 60;
        #pragma unroll 4
        for (int d4 = 0; d4 < 64; d4 += 4) {
            float4 Aq[4], Cq[4], Kv[4], Rv[7];
            #pragma unroll
            for (int i = 0; i < 4; ++i) {
                Aq[i] = *(float4*)&qu[ti * 4 + i][d4];
                Cq[i] = *(float4*)&qv[ti * 4 + i][d4];
                Kv[i] = *(float4*)&Kt[tj * 4 + i][d4];
            }
            #pragma unroll
            for (int t = 0; t < 7; ++t)
                Rv[t] = *(float4*)&RKs[jlb + t][d4];
            #pragma unroll
            for (int i = 0; i < 4; ++i)
                #pragma unroll
                for (int j = 0; j < 4; ++j) {
                    float4 kk = Kv[j];
                    float4 rr = Rv[j - i + 3];
                    acc[i][j] += Aq[i].x * kk.x + Aq[i].y * kk.y + Aq[i].z * kk.z + Aq[i].w * kk.w
                               + Cq[i].x * rr.x + Cq[i].y * rr.y + Cq[i].z * rr.z + Cq[i].w * rr.w;
                }
        }
        #pragma unroll
        for (int i = 0; i < 4; ++i) {
            int gi = i0 + ti * 4 + i;
            float mx = -1e30f;
            #pragma unroll
            for (int j = 0; j < 4; ++j) {
                int gj = j0 + tj * 4 + j;
                float vS = acc[i][j] * 0.125f;
                if (gj > gi + 512) vS = -1e30f;
                acc[i][j] = vS;
                mx = fmaxf(mx, vS);
            }
            pmax[ti * 4 + i][tj] = mx;
        }
        __syncthreads();
        if (tid < 64) {
            float mo = mrow[tid], mn = mo;
            #pragma unroll
            for (int t = 0; t < 16; ++t) mn = fmaxf(mn, pmax[tid][t]);
            mrow[tid] = mn;
            scalef[tid] = __expf(mo - mn);
        }
        __syncthreads();
        #pragma unroll
        for (int i = 0; i < 4; ++i) {
            int ri = ti * 4 + i;
            float mn = mrow[ri];
            float4 pv;
            pv.x = __expf(acc[i][0] - mn);
            pv.y = __expf(acc[i][1] - mn);
            pv.z = __expf(acc[i][2] - mn);
            pv.w = __expf(acc[i][3] - mn);
            *(float4*)&S[ri][tj * 4] = pv;
            psum[ri][tj] = pv.x + pv.y + pv.z + pv.w;
            float scl = scalef[ri];
            #pragma unroll
            for (int j2 = 0; j2 < 4; ++j2) Od[i][j2] *= scl;
        }
        __syncthreads();
        if (tid < 64) {
            float s = 0.f;
            #pragma unroll
            for (int t = 0; t < 16; ++t) s += psum[tid][t];
            lrow[tid] = lrow[tid] * scalef[tid] + s;
        }
        #pragma unroll 4
        for (int jb = 0; jb < 64; jb += 4) {
            float4 p0 = *(float4*)&S[ti * 4 + 0][jb];
            float4 p1 = *(float4*)&S[ti * 4 + 1][jb];
            float4 p2 = *(float4*)&S[ti * 4 + 2][jb];
            float4 p3 = *(float4*)&S[ti * 4 + 3][jb];
            float4 v0 = *(float4*)&Vt[jb + 0][tj * 4];
            float4 v1 = *(float4*)&Vt[jb + 1][tj * 4];
            float4 v2 = *(float4*)&Vt[jb + 2][tj * 4];
            float4 v3 = *(float4*)&Vt[jb + 3][tj * 4];
            float4 pr[4] = {p0, p1, p2, p3};
            #pragma unroll
            for (int i = 0; i < 4; ++i) {
                Od[i][0] += pr[i].x * v0.x + pr[i].y * v1.x + pr[i].z * v2.x + pr[i].w * v3.x;
                Od[i][1] += pr[i].x * v0.y + pr[i].y * v1.y + pr[i].z * v2.y + pr[i].w * v3.y;
                Od[i][2] += pr[i].x * v0.z + pr[i].y * v1.z + pr[i].z * v2.z + pr[i].w * v3.z;
                Od[i][3] += pr[i].x * v0.w + pr[i].y * v1.w + pr[i].z * v2.w + pr[i].w * v3.w;
            }
        }
    }
    __syncthreads();
    #pragma unroll
    for (int i = 0; i < 4; ++i) {
        int ri = ti * 4 + i;
        float inv = 1.f / lrow[ri];
        float4 o = make_float4(Od[i][0] * inv, Od[i][1] * inv, Od[i][2] * inv, Od[i][3] * inv);
        *(float4*)&y1[((size_t)(i0 + ri) * 8 + b) * 1024 + h * 64 + tj * 4] = o;
    }
}

// ---------------------------------------------------------------------------
// Persistent GRU with LIGHTWEIGHT custom barrier (replaces cg::grid.sync).
// 128 blocks x 512 threads, cooperative launch (co-residency guaranteed).
// Wave w owns output dim d = blockIdx*8 + w; Whh rows in registers.
// Cross-XCD protocol per step:
//   h stores  : relaxed agent atomic stores (sc0 sc1, write-through coherent)
//   arrive    : one RELEASE fetch_add per block on a monotone counter
//   wait      : relaxed spin + final ACQUIRE load (tid 0 only)
//   re-read   : per-wave `buffer_inv sc1` (inv L1+L2 clean lines), then
//               NORMAL vectorized float4 loads of h.
// ---------------------------------------------------------------------------
__global__ __launch_bounds__(512) void gru_persistent(
    const float* __restrict__ h0, float* __restrict__ hA, float* __restrict__ hB,
    const float* __restrict__ Whh, const float* __restrict__ bhh,
    const float* __restrict__ xg, float* __restrict__ out,
    unsigned* __restrict__ bar)
{
    int lane = threadIdx.x & 63;
    int wave = threadIdx.x >> 6;
    int d = blockIdx.x * 8 + wave;
    int kb = lane << 4;

    float4 wgt[3][4];
    #pragma unroll
    for (int g = 0; g < 3; ++g)
        #pragma unroll
        for (int q = 0; q < 4; ++q)
            wgt[g][q] = *(const float4*)&Whh[(size_t)(g * 1024 + d) * 1024 + kb + q * 4];
    float b_r = bhh[d], b_z = bhh[1024 + d], b_n = bhh[2048 + d];

    for (int t = 0; t < 512; ++t) {
        const float* hi_ = (t == 0) ? h0 : ((t & 1) ? hA : hB);
        float* ho = (t & 1) ? hB : hA;

        // early independent loads
        float xr = 0.f, xz = 0.f, xn = 0.f, hprev = 0.f;
        if (lane < 8) {
            size_t xb = ((size_t)t * 8 + lane) * 3072 + d;
            xr = xg[xb];
            xz = xg[xb + 1024];
            xn = xg[xb + 2048];
            hprev = hi_[lane * 1024 + d];
        }

        float acc[3][8];
        #pragma unroll
        for (int g = 0; g < 3; ++g)
            #pragma unroll
            for (int b = 0; b < 8; ++b) acc[g][b] = 0.f;

        #pragma unroll
        for (int b = 0; b < 8; ++b) {
            const float* hb = hi_ + b * 1024 + kb;
            float4 h0v = *(const float4*)(hb);
            float4 h1v = *(const float4*)(hb + 4);
            float4 h2v = *(const float4*)(hb + 8);
            float4 h3v = *(const float4*)(hb + 12);
            #pragma unroll
            for (int g = 0; g < 3; ++g) {
                acc[g][b] += wgt[g][0].x * h0v.x + wgt[g][0].y * h0v.y + wgt[g][0].z * h0v.z + wgt[g][0].w * h0v.w
                           + wgt[g][1].x * h1v.x + wgt[g][1].y * h1v.y + wgt[g][1].z * h1v.z + wgt[g][1].w * h1v.w
                           + wgt[g][2].x * h2v.x + wgt[g][2].y * h2v.y + wgt[g][2].z * h2v.z + wgt[g][2].w * h2v.w
                           + wgt[g][3].x * h3v.x + wgt[g][3].y * h3v.y + wgt[g][3].z * h3v.z + wgt[g][3].w * h3v.w;
            }
        }
        #pragma unroll
        for (int g = 0; g < 3; ++g)
            #pragma unroll
            for (int b = 0; b < 8; ++b) {
                float v = acc[g][b];
                v += __shfl_xor(v, 32);
                v += __shfl_xor(v, 16);
                v += __shfl_xor(v, 8);
                v += __shfl_xor(v, 4);
                v += __shfl_xor(v, 2);
                v += __shfl_xor(v, 1);
                acc[g][b] = v;
            }

        if (lane < 8) {
            float s0 = acc[0][0], s1 = acc[1][0], s2 = acc[2][0];
            #pragma unroll
            for (int b = 1; b < 8; ++b)
                if (lane == b) { s0 = acc[0][b]; s1 = acc[1][b]; s2 = acc[2][b]; }
            float rr = 1.f / (1.f + __expf(-(xr + s0 + b_r)));
            float zz = 1.f / (1.f + __expf(-(xz + s1 + b_z)));
            float nn = tanhf(xn + rr * (s2 + b_n));
            float hn = (1.f - zz) * nn + zz * hprev;
            // coherent (sc0 sc1) store so consumers on other XCDs see it
            __hip_atomic_store(&ho[lane * 1024 + d], hn, __ATOMIC_RELAXED,
                               __HIP_MEMORY_SCOPE_AGENT);
            out[((size_t)t * 8 + lane) * 1024 + d] = hn;   // normal store (read after kernel end)
        }

        if (t != 511) {
            __syncthreads();              // drains vmcnt: all waves' h stores at coherent point
            if (threadIdx.x == 0) {
                __hip_atomic_fetch_add(bar, 1u, __ATOMIC_RELEASE, __HIP_MEMORY_SCOPE_AGENT);
                unsigned tgt = 128u * (unsigned)(t + 1);
                while (__hip_atomic_load(bar, __ATOMIC_RELAXED, __HIP_MEMORY_SCOPE_AGENT) < tgt) {}
                (void)__hip_atomic_load(bar, __ATOMIC_ACQUIRE, __HIP_MEMORY_SCOPE_AGENT);
            }
            __syncthreads();
            // per-wave invalidate of L1 + (XCD) L2 clean lines, so the normal
            // float4 h loads below cannot hit stale cache. Whh lives in
            // registers and xg has no reuse -> inv costs ~nothing.
            asm volatile("buffer_inv sc1" ::: "memory");
        }
    }
}

// ---------------------------------------------------------------------------
// Fallback GRU step (512 launches) if cooperative launch is unavailable.
// ---------------------------------------------------------------------------
__global__ __launch_bounds__(256) void gru_step(
    const float* __restrict__ hin, float* __restrict__ hout,
    const float* __restrict__ Whh, const float* __restrict__ bhh,
    const float* __restrict__ xg, float* __restrict__ out, int step)
{
    __shared__ float hs[8192];
    __shared__ float red[24][256];
    int tid = threadIdx.x;
    int w = blockIdx.x;

    #pragma unroll
    for (int q = 0; q < 8; ++q) {
        int i4 = q * 256 + tid;
        *(float4*)&hs[i4 * 4] = *(const float4*)&hin[i4 * 4];
    }
    __syncthreads();

    int dd = tid & 15, kc = tid >> 4;
    int d = w * 16 + dd;
    float acc0[8] = {}, acc1[8] = {}, acc2[8] = {};
    const float* w0 = Whh + (size_t)d * 1024 + kc * 64;
    const float* w1 = Whh + (size_t)(1024 + d) * 1024 + kc * 64;
    const float* w2 = Whh + (size_t)(2048 + d) * 1024 + kc * 64;
    #pragma unroll 4
    for (int k4 = 0; k4 < 64; k4 += 4) {
        float4 wr = *(const float4*)(w0 + k4);
        float4 wz = *(const float4*)(w1 + k4);
        float4 wn = *(const float4*)(w2 + k4);
        int kbase = kc * 64 + k4;
        #pragma unroll
        for (int b = 0; b < 8; ++b) {
            float4 h4 = *(const float4*)&hs[b * 1024 + kbase];
            acc0[b] += wr.x * h4.x + wr.y * h4.y + wr.z * h4.z + wr.w * h4.w;
            acc1[b] += wz.x * h4.x + wz.y * h4.y + wz.z * h4.z + wz.w * h4.w;
            acc2[b] += wn.x * h4.x + wn.y * h4.y + wn.z * h4.z + wn.w * h4.w;
        }
    }
    int c = kc * 16 + dd;
    #pragma unroll
    for (int b = 0; b < 8; ++b) {
        red[b][c]      = acc0[b];
        red[8 + b][c]  = acc1[b];
        red[16 + b][c] = acc2[b];
    }
    __syncthreads();

    if (tid < 128) {
        int b = tid >> 4, d2l = tid & 15;
        int d2 = w * 16 + d2l;
        float s0 = 0.f, s1 = 0.f, s2 = 0.f;
        #pragma unroll
        for (int k2 = 0; k2 < 16; ++k2) {
            s0 += red[b][k2 * 16 + d2l];
            s1 += red[8 + b][k2 * 16 + d2l];
            s2 += red[16 + b][k2 * 16 + d2l];
        }
        size_t xb = ((size_t)step * 8 + b) * 3072;
        float xr = xg[xb + d2];
        float xz = xg[xb + 1024 + d2];
        float xn = xg[xb + 2048 + d2];
        float r = 1.f / (1.f + __expf(-(xr + s0 + bhh[d2])));
        float z = 1.f / (1.f + __expf(-(xz + s1 + bhh[1024 + d2])));
        float n = tanhf(xn + r * (s2 + bhh[2048 + d2]));
        float hprev = hs[b * 1024 + d2];
        float hnew = (1.f - z) * n + z * hprev;
        hout[b * 1024 + d2] = hnew;
        out[((size_t)step * 8 + b) * 1024 + d2] = hnew;
    }
}

// ---------------------------------------------------------------------------
extern "C" void kernel_launch(void* const* d_in, const int* in_sizes, int n_in,
                              void* d_out, int out_size, void* d_ws, size_t ws_size,
                              hipStream_t stream) {
    (void)in_sizes; (void)n_in; (void)out_size; (void)ws_size;
    const float* inputs = (const float*)d_in[0];
    const float* r_in   = (const float*)d_in[1];
    const float* u_in   = (const float*)d_in[2];
    const float* v_in   = (const float*)d_in[3];
    const float* mem    = (const float*)d_in[4];
    const float* Wqkv   = (const float*)d_in[5];
    const float* Wr     = (const float*)d_in[6];
    const float* Wo     = (const float*)d_in[7];
    const float* Wih    = (const float*)d_in[8];
    const float* Whh    = (const float*)d_in[9];
    const float* bih    = (const float*)d_in[10];
    const float* bhh    = (const float*)d_in[11];
    const float* h0     = (const float*)d_in[12];
    float* out = (float*)d_out;
    float* ws = (float*)d_ws;

    float*    qkv   = ws;                       // 25165824
    float*    rk    = ws + 25165824;            //  1048576
    float*    y1    = ws + 26214400;            //  4194304
    float*    y2    = ws + 30408704;            //  4194304
    float*    xg    = ws + 34603008;            // 12582912
    float*    hA    = ws + 47185920;            //     8192
    float*    hB    = ws + 47194112;            //     8192
    unsigned* WqkvP = (unsigned*)(ws + 47202304);   // 3145728
    unsigned* WrP   = (unsigned*)(ws + 50348032);   // 1048576
    unsigned* WoP   = (unsigned*)(ws + 51396608);   // 1048576
    unsigned* WihP  = (unsigned*)(ws + 52445184);   // 3145728
    unsigned* bar   = (unsigned*)(ws + 55590912);   // 1 counter

    dim3 blk(256);
    // ---- weight prep (bf16 hi/lo split, pre-swizzled [n][k])
    prep_w<true ><<<1536, blk, 0, stream>>>(Wqkv, WqkvP, 3072, 1024, 3072);
    prep_w<true ><<< 512, blk, 0, stream>>>(Wr,   WrP,   1024, 1024, 1024);
    prep_w<true ><<< 512, blk, 0, stream>>>(Wo,   WoP,   1024, 1024, 1024);
    prep_w<false><<<1536, blk, 0, stream>>>(Wih,  WihP,  3072, 1024, 1024);
    hipMemsetAsync(bar, 0, sizeof(unsigned), stream);   // zero barrier counter (every launch)

    // ---- qkv = [mem; inputs] @ W_qkv   (8192 x 3072, K=1024)
    gemm_mfma<1, false><<<dim3(24, 64), blk, 0, stream>>>(
        mem, inputs, WqkvP, nullptr, qkv, 8192, 3072, 1024, 1024, 3072);
    // ---- rk = r @ W_r                  (1024 x 1024)
    gemm_mfma<0, false><<<dim3(8, 8), blk, 0, stream>>>(
        r_in, nullptr, WrP, nullptr, rk, 1024, 1024, 1024, 1024, 1024);
    // ---- fused attention -> y1
    attn_fused<<<dim3(8, 8, 16), blk, 0, stream>>>(qkv, rk, u_in, v_in, y1);
    // ---- y2 = y1 @ W_o                 (4096 x 1024)
    gemm_mfma<0, false><<<dim3(8, 32), blk, 0, stream>>>(
        y1, nullptr, WoP, nullptr, y2, 4096, 1024, 1024, 1024, 1024);
    // ---- xg = y2 @ W_ih^T + b_ih       (4096 x 3072)
    gemm_mfma<0, true><<<dim3(24, 32), blk, 0, stream>>>(
        y2, nullptr, WihP, bih, xg, 4096, 3072, 1024, 1024, 3072);

    // ---- GRU recurrence: persistent cooperative kernel (fallback: 512 launches)
    {
        const float* a0 = h0; float* a1 = hA; float* a2 = hB;
        const float* a3 = Whh; const float* a4 = bhh; const float* a5 = xg;
        float* a6 = out; unsigned* a7 = bar;
        void* args[8] = {&a0, &a1, &a2, &a3, &a4, &a5, &a6, &a7};
        hipError_t e = hipLaunchCooperativeKernel((void*)gru_persistent,
                                                  dim3(128), dim3(512), args, 0, stream);
        if (e != hipSuccess) {
            const float* hin = h0;
            for (int s = 0; s < 512; ++s) {
                float* hp = (s & 1) ? hB : hA;
                gru_step<<<64, blk, 0, stream>>>(hin, hp, Whh, bhh, xg, out, s);
                hin = hp;
            }
        }
    }
}

// Round 4
// 5876.929 us; speedup vs baseline: 2.2840x; 2.0707x over previous
//
#include <hip/hip_runtime.h>
#include <math.h>

// D_MODEL=1024, N_HEADS=16, D_HEAD=64, QLEN=512, MLEN=512, KLEN=1024, BATCH=8

typedef short bf16x8 __attribute__((ext_vector_type(8)));
typedef float f32x4 __attribute__((ext_vector_type(4)));

union FragU { uint4 u; bf16x8 h; };

// split two fp32 into packed bf16-hi (truncated) and bf16-lo (exact residual, truncated)
__device__ inline void split2(float x0, float x1, unsigned& hi, unsigned& lo) {
    unsigned u0 = __float_as_uint(x0), u1 = __float_as_uint(x1);
    float h0 = __uint_as_float(u0 & 0xffff0000u);
    float h1 = __uint_as_float(u1 & 0xffff0000u);
    unsigned l0 = __float_as_uint(x0 - h0), l1 = __float_as_uint(x1 - h1);
    hi = (u0 >> 16) | (u1 & 0xffff0000u);
    lo = (l0 >> 16) | (l1 & 0xffff0000u);
}

// ---------------------------------------------------------------------------
// Weight prep for GEMMs: W (fp32, [n][k] if !TR else [k][n]) -> u32[n][K],
// 32-k tile = 8 16B slots {hi,lo,...} XOR-swizzled by (n&7).
// ---------------------------------------------------------------------------
template<bool TR>
__global__ __launch_bounds__(256) void prep_w(
    const float* __restrict__ W, unsigned* __restrict__ out, int Nr, int K, int ldw)
{
    int idx = blockIdx.x * 256 + threadIdx.x;
    int cpr = K >> 3;
    if (idx >= Nr * cpr) return;
    int n, c;
    if (TR) { n = idx % Nr; c = idx / Nr; }
    else    { c = idx % cpr; n = idx / cpr; }
    int kt = c >> 2, j = c & 3;
    int k = kt * 32 + j * 8;
    float x[8];
    #pragma unroll
    for (int i = 0; i < 8; ++i)
        x[i] = TR ? W[(size_t)(k + i) * ldw + n] : W[(size_t)n * ldw + k + i];
    unsigned h[4], l[4];
    split2(x[0], x[1], h[0], l[0]);
    split2(x[2], x[3], h[1], l[1]);
    split2(x[4], x[5], h[2], l[2]);
    split2(x[6], x[7], h[3], l[3]);
    unsigned* base = out + (size_t)n * K + kt * 32;
    *(uint4*)(base + (((2 * j) ^ (n & 7)) * 4))     = make_uint4(h[0], h[1], h[2], h[3]);
    *(uint4*)(base + (((2 * j + 1) ^ (n & 7)) * 4)) = make_uint4(l[0], l[1], l[2], l[3]);
}

// ---------------------------------------------------------------------------
// Split-bf16 MFMA GEMM (unchanged; verified rounds 1-3).
// ---------------------------------------------------------------------------
template<int AMODE, bool BIAS>
__global__ __launch_bounds__(256) void gemm_mfma(
    const float* __restrict__ A, const float* __restrict__ A2,
    const unsigned* __restrict__ Bp, const float* __restrict__ bias,
    float* __restrict__ C, int M, int N, int K, int lda, int ldc)
{
    __shared__ uint4 Ab[1024];
    __shared__ uint4 Bb[1024];
    int tid = threadIdx.x;
    int lane = tid & 63, wid = tid >> 6;
    int wr = wid >> 1, wc = wid & 1;
    int n0 = blockIdx.x * 128, m0 = blockIdx.y * 128;
    int r15 = lane & 15, s = lane >> 4;

    f32x4 acc[4][4];
    #pragma unroll
    for (int i = 0; i < 4; ++i)
        #pragma unroll
        for (int j = 0; j < 4; ++j) acc[i][j] = 0.0f;

    for (int kt = 0; kt < (K >> 5); ++kt) {
        int k0 = kt * 32;
        #pragma unroll
        for (int q = 0; q < 2; ++q) {
            int idx = q * 256 + tid;
            int row = idx >> 2, j = idx & 3;
            const float* ap;
            if (AMODE == 1) {
                int gm = m0 + row;
                ap = (gm < 4096) ? (A + (size_t)gm * lda) : (A2 + (size_t)(gm - 4096) * lda);
            } else {
                ap = A + (size_t)(m0 + row) * lda;
            }
            float4 x0 = *(const float4*)(ap + k0 + j * 8);
            float4 x1 = *(const float4*)(ap + k0 + j * 8 + 4);
            unsigned h[4], l[4];
            split2(x0.x, x0.y, h[0], l[0]);
            split2(x0.z, x0.w, h[1], l[1]);
            split2(x1.x, x1.y, h[2], l[2]);
            split2(x1.z, x1.w, h[3], l[3]);
            Ab[row * 8 + (((2 * j) ^ (row & 7)))]     = make_uint4(h[0], h[1], h[2], h[3]);
            Ab[row * 8 + (((2 * j + 1) ^ (row & 7)))] = make_uint4(l[0], l[1], l[2], l[3]);
        }
        #pragma unroll
        for (int q = 0; q < 4; ++q) {
            int idx = q * 256 + tid;
            int row = idx >> 3, slot = idx & 7;
            Bb[idx] = *(const uint4*)(Bp + (size_t)(n0 + row) * K + k0 + slot * 4);
        }
        __syncthreads();
        FragU ahi[4], alo[4], bhi[4], blo[4];
        #pragma unroll
        for (int f = 0; f < 4; ++f) {
            int ar = wr * 64 + f * 16 + r15;
            ahi[f].u = Ab[ar * 8 + ((2 * s) ^ (ar & 7))];
            alo[f].u = Ab[ar * 8 + ((2 * s + 1) ^ (ar & 7))];
            int br = wc * 64 + f * 16 + r15;
            bhi[f].u = Bb[br * 8 + ((2 * s) ^ (br & 7))];
            blo[f].u = Bb[br * 8 + ((2 * s + 1) ^ (br & 7))];
        }
        #pragma unroll
        for (int fi = 0; fi < 4; ++fi)
            #pragma unroll
            for (int fj = 0; fj < 4; ++fj) {
                acc[fi][fj] = __builtin_amdgcn_mfma_f32_16x16x32_bf16(ahi[fi].h, bhi[fj].h, acc[fi][fj], 0, 0, 0);
                acc[fi][fj] = __builtin_amdgcn_mfma_f32_16x16x32_bf16(ahi[fi].h, blo[fj].h, acc[fi][fj], 0, 0, 0);
                acc[fi][fj] = __builtin_amdgcn_mfma_f32_16x16x32_bf16(alo[fi].h, bhi[fj].h, acc[fi][fj], 0, 0, 0);
            }
        __syncthreads();
    }
    int r4 = (lane >> 4) * 4;
    #pragma unroll
    for (int fj = 0; fj < 4; ++fj) {
        int n = n0 + wc * 64 + fj * 16 + r15;
        float bv = BIAS ? bias[n] : 0.f;
        #pragma unroll
        for (int fi = 0; fi < 4; ++fi) {
            int m = m0 + wr * 64 + fi * 16 + r4;
            #pragma unroll
            for (int r = 0; r < 4; ++r)
                C[(size_t)(m + r) * ldc + n] = acc[fi][fj][r] + bv;
        }
    }
}

// ---------------------------------------------------------------------------
// Fused TXL attention (unchanged, fp32).
// ---------------------------------------------------------------------------
__global__ __launch_bounds__(256) void attn_fused(
    const float* __restrict__ qkv, const float* __restrict__ rk,
    const float* __restrict__ u_, const float* __restrict__ v_,
    float* __restrict__ y1)
{
    __shared__ float qu[64][68], qv[64][68], Kt[64][68], Vt[64][68];
    __shared__ float RKs[128][68];
    __shared__ float S[64][68];
    __shared__ float mrow[64], lrow[64], scalef[64];
    __shared__ float pmax[64][16], psum[64][16];

    int tid = threadIdx.x;
    int it = blockIdx.x, b = blockIdx.y, h = blockIdx.z;
    int i0 = it * 64;
    int ti = tid >> 4, tj = tid & 15;

    {
        int r = tid >> 2, c0 = (tid & 3) * 16;
        size_t base = ((size_t)(i0 + r + 512) * 8 + b) * 3072 + h * 64;
        #pragma unroll
        for (int q = 0; q < 4; ++q) {
            int c = c0 + q * 4;
            float4 qq = *(const float4*)&qkv[base + c];
            float4 uu = *(const float4*)&u_[h * 64 + c];
            float4 vv = *(const float4*)&v_[h * 64 + c];
            *(float4*)&qu[r][c] = make_float4(qq.x + uu.x, qq.y + uu.y, qq.z + uu.z, qq.w + uu.w);
            *(float4*)&qv[r][c] = make_float4(qq.x + vv.x, qq.y + vv.y, qq.z + vv.z, qq.w + vv.w);
        }
    }
    if (tid < 64) { mrow[tid] = -1e30f; lrow[tid] = 0.f; }

    float Od[4][4] = {};
    int njt = it + 9;

    for (int jt = 0; jt < njt; ++jt) {
        int j0 = jt * 64;
        __syncthreads();
        {
            int r = tid >> 2, c0 = (tid & 3) * 16;
            size_t kb = ((size_t)(j0 + r) * 8 + b) * 3072 + 1024 + h * 64;
            #pragma unroll
            for (int q = 0; q < 4; ++q) {
                int c = c0 + q * 4;
                *(float4*)&Kt[r][c] = *(const float4*)&qkv[kb + c];
                *(float4*)&Vt[r][c] = *(const float4*)&qkv[kb + 1024 + c];
            }
        }
        {
            int r2 = tid >> 1, c0 = (tid & 1) * 32;
            int jj = j0 - i0 + 448 + r2;
            jj = jj < 0 ? 0 : (jj > 1023 ? 1023 : jj);
            size_t rb = (size_t)jj * 1024 + h * 64;
            #pragma unroll
            for (int q = 0; q < 8; ++q) {
                int c = c0 + q * 4;
                *(float4*)&RKs[r2][c] = *(const float4*)&rk[rb + c];
            }
        }
        __syncthreads();

        float acc[4][4] = {};
        int jlb = (tj - ti) * 4 + 60;
        #pragma unroll 4
        for (int d4 = 0; d4 < 64; d4 += 4) {
            float4 Aq[4], Cq[4], Kv[4], Rv[7];
            #pragma unroll
            for (int i = 0; i < 4; ++i) {
                Aq[i] = *(float4*)&qu[ti * 4 + i][d4];
                Cq[i] = *(float4*)&qv[ti * 4 + i][d4];
                Kv[i] = *(float4*)&Kt[tj * 4 + i][d4];
            }
            #pragma unroll
            for (int t = 0; t < 7; ++t)
                Rv[t] = *(float4*)&RKs[jlb + t][d4];
            #pragma unroll
            for (int i = 0; i < 4; ++i)
                #pragma unroll
                for (int j = 0; j < 4; ++j) {
                    float4 kk = Kv[j];
                    float4 rr = Rv[j - i + 3];
                    acc[i][j] += Aq[i].x * kk.x + Aq[i].y * kk.y + Aq[i].z * kk.z + Aq[i].w * kk.w
                               + Cq[i].x * rr.x + Cq[i].y * rr.y + Cq[i].z * rr.z + Cq[i].w * rr.w;
                }
        }
        #pragma unroll
        for (int i = 0; i < 4; ++i) {
            int gi = i0 + ti * 4 + i;
            float mx = -1e30f;
            #pragma unroll
            for (int j = 0; j < 4; ++j) {
                int gj = j0 + tj * 4 + j;
                float vS = acc[i][j] * 0.125f;
                if (gj > gi + 512) vS = -1e30f;
                acc[i][j] = vS;
                mx = fmaxf(mx, vS);
            }
            pmax[ti * 4 + i][tj] = mx;
        }
        __syncthreads();
        if (tid < 64) {
            float mo = mrow[tid], mn = mo;
            #pragma unroll
            for (int t = 0; t < 16; ++t) mn = fmaxf(mn, pmax[tid][t]);
            mrow[tid] = mn;
            scalef[tid] = __expf(mo - mn);
        }
        __syncthreads();
        #pragma unroll
        for (int i = 0; i < 4; ++i) {
            int ri = ti * 4 + i;
            float mn = mrow[ri];
            float4 pv;
            pv.x = __expf(acc[i][0] - mn);
            pv.y = __expf(acc[i][1] - mn);
            pv.z = __expf(acc[i][2] - mn);
            pv.w = __expf(acc[i][3] - mn);
            *(float4*)&S[ri][tj * 4] = pv;
            psum[ri][tj] = pv.x + pv.y + pv.z + pv.w;
            float scl = scalef[ri];
            #pragma unroll
            for (int j2 = 0; j2 < 4; ++j2) Od[i][j2] *= scl;
        }
        __syncthreads();
        if (tid < 64) {
            float s = 0.f;
            #pragma unroll
            for (int t = 0; t < 16; ++t) s += psum[tid][t];
            lrow[tid] = lrow[tid] * scalef[tid] + s;
        }
        #pragma unroll 4
        for (int jb = 0; jb < 64; jb += 4) {
            float4 p0 = *(float4*)&S[ti * 4 + 0][jb];
            float4 p1 = *(float4*)&S[ti * 4 + 1][jb];
            float4 p2 = *(float4*)&S[ti * 4 + 2][jb];
            float4 p3 = *(float4*)&S[ti * 4 + 3][jb];
            float4 v0 = *(float4*)&Vt[jb + 0][tj * 4];
            float4 v1 = *(float4*)&Vt[jb + 1][tj * 4];
            float4 v2 = *(float4*)&Vt[jb + 2][tj * 4];
            float4 v3 = *(float4*)&Vt[jb + 3][tj * 4];
            float4 pr[4] = {p0, p1, p2, p3};
            #pragma unroll
            for (int i = 0; i < 4; ++i) {
                Od[i][0] += pr[i].x * v0.x + pr[i].y * v1.x + pr[i].z * v2.x + pr[i].w * v3.x;
                Od[i][1] += pr[i].x * v0.y + pr[i].y * v1.y + pr[i].z * v2.y + pr[i].w * v3.y;
                Od[i][2] += pr[i].x * v0.z + pr[i].y * v1.z + pr[i].z * v2.z + pr[i].w * v3.z;
                Od[i][3] += pr[i].x * v0.w + pr[i].y * v1.w + pr[i].z * v2.w + pr[i].w * v3.w;
            }
        }
    }
    __syncthreads();
    #pragma unroll
    for (int i = 0; i < 4; ++i) {
        int ri = ti * 4 + i;
        float inv = 1.f / lrow[ri];
        float4 o = make_float4(Od[i][0] * inv, Od[i][1] * inv, Od[i][2] * inv, Od[i][3] * inv);
        *(float4*)&y1[((size_t)(i0 + ri) * 8 + b) * 1024 + h * 64 + tj * 4] = o;
    }
}

// ---------------------------------------------------------------------------
// Whh -> MFMA A-fragment layout (hi/lo planes).
// Row-tile rt (192 = 3 gates x 64 dim-groups): rows n = rt*16 + (lane&15),
// k-octet = lane>>4. Output: [rt][kt32][plane2][lane64] of 16B.
// ---------------------------------------------------------------------------
__global__ __launch_bounds__(256) void prep_whh(
    const float* __restrict__ Whh, uint4* __restrict__ outp)
{
    int idx = blockIdx.x * 256 + threadIdx.x;   // 192*32*64 = 393216
    if (idx >= 192 * 32 * 64) return;
    int lane = idx & 63, kt = (idx >> 6) & 31, rt = idx >> 11;
    int n = rt * 16 + (lane & 15);
    int k = kt * 32 + (lane >> 4) * 8;
    const float* src = Whh + (size_t)n * 1024 + k;
    float4 x0 = *(const float4*)src, x1 = *(const float4*)(src + 4);
    unsigned h[4], l[4];
    split2(x0.x, x0.y, h[0], l[0]);
    split2(x0.z, x0.w, h[1], l[1]);
    split2(x1.x, x1.y, h[2], l[2]);
    split2(x1.z, x1.w, h[3], l[3]);
    outp[((size_t)(rt * 32 + kt) * 2 + 0) * 64 + lane] = make_uint4(h[0], h[1], h[2], h[3]);
    outp[((size_t)(rt * 32 + kt) * 2 + 1) * 64 + lane] = make_uint4(l[0], l[1], l[2], l[3]);
}

// ---------------------------------------------------------------------------
// One GRU step via MFMA. 64 blocks x 192 threads (3 waves).
// Block g64 owns dims [g64*16, g64*16+16); wave wv computes gate wv
// (Whh row-tile rt = wv*64 + g64) over full K=1024: 32 kt x 3 split-MFMA.
// h (8 batches, cols 0..7 of B; cols 8..15 garbage/unused) is built into LDS
// as split-bf16 B-fragments each step. Gate combine via tiny LDS gather.
// ---------------------------------------------------------------------------
__global__ __launch_bounds__(192) void gru_step_mfma(
    const float* __restrict__ hin, float* __restrict__ hout,
    const uint4* __restrict__ WhhP, const float* __restrict__ bhh,
    const float* __restrict__ xg, float* __restrict__ out, int t)
{
    __shared__ uint4 Bf[32 * 2 * 64];    // [kt][plane][lane] 64 KB
    __shared__ float red[3][64][4];
    int tid = threadIdx.x;
    int lane = tid & 63, wv = tid >> 6;
    int g64 = blockIdx.x;

    // epilogue operand prefetch (independent of MFMA work)
    int col = lane & 15;                 // batch
    int d0 = g64 * 16 + (lane >> 4) * 4; // dim quad base
    bool act = (wv == 0) && (col < 8);
    float4 xr4, xz4, xn4, hp4, br4, bz4, bn4;
    if (act) {
        size_t xb = ((size_t)t * 8 + col) * 3072 + d0;
        xr4 = *(const float4*)&xg[xb];
        xz4 = *(const float4*)&xg[xb + 1024];
        xn4 = *(const float4*)&xg[xb + 2048];
        hp4 = *(const float4*)&hin[col * 1024 + d0];
        br4 = *(const float4*)&bhh[d0];
        bz4 = *(const float4*)&bhh[1024 + d0];
        bn4 = *(const float4*)&bhh[2048 + d0];
    }

    // build B (h) split-bf16 fragments: slots (kt32, oct4, b8) = 1024
    for (int s = tid; s < 1024; s += 192) {
        int b = s & 7, oct = (s >> 3) & 3, kt = s >> 5;
        const float* hp = hin + b * 1024 + kt * 32 + oct * 8;
        float4 x0 = *(const float4*)hp, x1 = *(const float4*)(hp + 4);
        unsigned hh[4], ll[4];
        split2(x0.x, x0.y, hh[0], ll[0]);
        split2(x0.z, x0.w, hh[1], ll[1]);
        split2(x1.x, x1.y, hh[2], ll[2]);
        split2(x1.z, x1.w, hh[3], ll[3]);
        int ln = oct * 16 + b;
        Bf[(kt * 2 + 0) * 64 + ln] = make_uint4(hh[0], hh[1], hh[2], hh[3]);
        Bf[(kt * 2 + 1) * 64 + ln] = make_uint4(ll[0], ll[1], ll[2], ll[3]);
    }
    __syncthreads();

    // MFMA: A = Whh fragments (global, L2-resident), B = h fragments (LDS)
    f32x4 acc = 0.0f;
    const uint4* wb = WhhP + ((size_t)(wv * 64 + g64) * 32) * 2 * 64;
    #pragma unroll 4
    for (int kt = 0; kt < 32; ++kt) {
        FragU ah_, al_, bh_, bl_;
        ah_.u = wb[(kt * 2 + 0) * 64 + lane];
        al_.u = wb[(kt * 2 + 1) * 64 + lane];
        bh_.u = Bf[(kt * 2 + 0) * 64 + lane];
        bl_.u = Bf[(kt * 2 + 1) * 64 + lane];
        acc = __builtin_amdgcn_mfma_f32_16x16x32_bf16(ah_.h, bh_.h, acc, 0, 0, 0);
        acc = __builtin_amdgcn_mfma_f32_16x16x32_bf16(ah_.h, bl_.h, acc, 0, 0, 0);
        acc = __builtin_amdgcn_mfma_f32_16x16x32_bf16(al_.h, bh_.h, acc, 0, 0, 0);
    }
    *(f32x4*)&red[wv][lane][0] = acc;
    __syncthreads();

    if (act) {
        f32x4 aR = *(f32x4*)&red[0][lane][0];
        f32x4 aZ = *(f32x4*)&red[1][lane][0];
        f32x4 aN = *(f32x4*)&red[2][lane][0];
        float hn[4];
        float xr[4] = {xr4.x, xr4.y, xr4.z, xr4.w};
        float xz[4] = {xz4.x, xz4.y, xz4.z, xz4.w};
        float xn[4] = {xn4.x, xn4.y, xn4.z, xn4.w};
        float hp[4] = {hp4.x, hp4.y, hp4.z, hp4.w};
        float br[4] = {br4.x, br4.y, br4.z, br4.w};
        float bz[4] = {bz4.x, bz4.y, bz4.z, bz4.w};
        float bn[4] = {bn4.x, bn4.y, bn4.z, bn4.w};
        #pragma unroll
        for (int r = 0; r < 4; ++r) {
            float rr = 1.f / (1.f + __expf(-(xr[r] + aR[r] + br[r])));
            float zz = 1.f / (1.f + __expf(-(xz[r] + aZ[r] + bz[r])));
            float nn = tanhf(xn[r] + rr * (aN[r] + bn[r]));
            hn[r] = (1.f - zz) * nn + zz * hp[r];
        }
        float4 hv = make_float4(hn[0], hn[1], hn[2], hn[3]);
        *(float4*)&hout[col * 1024 + d0] = hv;
        *(float4*)&out[((size_t)t * 8 + col) * 1024 + d0] = hv;
    }
}

// ---------------------------------------------------------------------------
extern "C" void kernel_launch(void* const* d_in, const int* in_sizes, int n_in,
                              void* d_out, int out_size, void* d_ws, size_t ws_size,
                              hipStream_t stream) {
    (void)in_sizes; (void)n_in; (void)out_size; (void)ws_size;
    const float* inputs = (const float*)d_in[0];
    const float* r_in   = (const float*)d_in[1];
    const float* u_in   = (const float*)d_in[2];
    const float* v_in   = (const float*)d_in[3];
    const float* mem    = (const float*)d_in[4];
    const float* Wqkv   = (const float*)d_in[5];
    const float* Wr     = (const float*)d_in[6];
    const float* Wo     = (const float*)d_in[7];
    const float* Wih    = (const float*)d_in[8];
    const float* Whh    = (const float*)d_in[9];
    const float* bih    = (const float*)d_in[10];
    const float* bhh    = (const float*)d_in[11];
    const float* h0     = (const float*)d_in[12];
    float* out = (float*)d_out;
    float* ws = (float*)d_ws;

    float*    qkv   = ws;                       // 25165824 (dead after attn; reused for WhhP)
    float*    rk    = ws + 25165824;            //  1048576
    float*    y1    = ws + 26214400;            //  4194304
    float*    y2    = ws + 30408704;            //  4194304
    float*    xg    = ws + 34603008;            // 12582912
    float*    hA    = ws + 47185920;            //     8192
    float*    hB    = ws + 47194112;            //     8192
    unsigned* WqkvP = (unsigned*)(ws + 47202304);   // 3145728
    unsigned* WrP   = (unsigned*)(ws + 50348032);   // 1048576
    unsigned* WoP   = (unsigned*)(ws + 51396608);   // 1048576
    unsigned* WihP  = (unsigned*)(ws + 52445184);   // 3145728
    uint4*    WhhP  = (uint4*)qkv;                  // 786432 uint4 = 12.6 MB

    dim3 blk(256);
    // ---- weight prep (GEMM layouts)
    prep_w<true ><<<1536, blk, 0, stream>>>(Wqkv, WqkvP, 3072, 1024, 3072);
    prep_w<true ><<< 512, blk, 0, stream>>>(Wr,   WrP,   1024, 1024, 1024);
    prep_w<true ><<< 512, blk, 0, stream>>>(Wo,   WoP,   1024, 1024, 1024);
    prep_w<false><<<1536, blk, 0, stream>>>(Wih,  WihP,  3072, 1024, 1024);

    // ---- qkv = [mem; inputs] @ W_qkv   (8192 x 3072, K=1024)
    gemm_mfma<1, false><<<dim3(24, 64), blk, 0, stream>>>(
        mem, inputs, WqkvP, nullptr, qkv, 8192, 3072, 1024, 1024, 3072);
    // ---- rk = r @ W_r                  (1024 x 1024)
    gemm_mfma<0, false><<<dim3(8, 8), blk, 0, stream>>>(
        r_in, nullptr, WrP, nullptr, rk, 1024, 1024, 1024, 1024, 1024);
    // ---- fused attention -> y1
    attn_fused<<<dim3(8, 8, 16), blk, 0, stream>>>(qkv, rk, u_in, v_in, y1);
    // ---- Whh fragment prep (into dead qkv space; after attn in-stream)
    prep_whh<<<1536, blk, 0, stream>>>(Whh, WhhP);
    // ---- y2 = y1 @ W_o                 (4096 x 1024)
    gemm_mfma<0, false><<<dim3(8, 32), blk, 0, stream>>>(
        y1, nullptr, WoP, nullptr, y2, 4096, 1024, 1024, 1024, 1024);
    // ---- xg = y2 @ W_ih^T + b_ih       (4096 x 3072)
    gemm_mfma<0, true><<<dim3(24, 32), blk, 0, stream>>>(
        y2, nullptr, WihP, bih, xg, 4096, 3072, 1024, 1024, 3072);

    // ---- GRU recurrence: 512 lean MFMA step-kernels
    const float* hin = h0;
    for (int s = 0; s < 512; ++s) {
        float* hp = (s & 1) ? hB : hA;
        gru_step_mfma<<<64, dim3(192), 0, stream>>>(hin, hp, WhhP, bhh, xg, out, s);
        hin = hp;
    }
}

// Round 5
// 5321.058 us; speedup vs baseline: 2.5226x; 1.1045x over previous
//
#include <hip/hip_runtime.h>
#include <math.h>

// D_MODEL=1024, N_HEADS=16, D_HEAD=64, QLEN=512, MLEN=512, KLEN=1024, BATCH=8

typedef short bf16x8 __attribute__((ext_vector_type(8)));
typedef float f32x4 __attribute__((ext_vector_type(4)));

union FragU { uint4 u; bf16x8 h; };

// split two fp32 into packed bf16-hi (truncated) and bf16-lo (exact residual, truncated)
__device__ inline void split2(float x0, float x1, unsigned& hi, unsigned& lo) {
    unsigned u0 = __float_as_uint(x0), u1 = __float_as_uint(x1);
    float h0 = __uint_as_float(u0 & 0xffff0000u);
    float h1 = __uint_as_float(u1 & 0xffff0000u);
    unsigned l0 = __float_as_uint(x0 - h0), l1 = __float_as_uint(x1 - h1);
    hi = (u0 >> 16) | (u1 & 0xffff0000u);
    lo = (l0 >> 16) | (l1 & 0xffff0000u);
}

// async 16B global -> LDS (dst uniform + lane*16 implicit)
__device__ __forceinline__ void gl_lds16(const uint4* g, uint4* l) {
    __builtin_amdgcn_global_load_lds(
        (const __attribute__((address_space(1))) uint4*)g,
        (__attribute__((address_space(3))) uint4*)l, 16, 0, 0);
}

// ---------------------------------------------------------------------------
// Weight prep for GEMMs: W (fp32, [n][k] if !TR else [k][n]) -> u32[n][K],
// 32-k tile = 8 16B slots {hi,lo,...} XOR-swizzled by (n&7).  (unchanged)
// ---------------------------------------------------------------------------
template<bool TR>
__global__ __launch_bounds__(256) void prep_w(
    const float* __restrict__ W, unsigned* __restrict__ out, int Nr, int K, int ldw)
{
    int idx = blockIdx.x * 256 + threadIdx.x;
    int cpr = K >> 3;
    if (idx >= Nr * cpr) return;
    int n, c;
    if (TR) { n = idx % Nr; c = idx / Nr; }
    else    { c = idx % cpr; n = idx / cpr; }
    int kt = c >> 2, j = c & 3;
    int k = kt * 32 + j * 8;
    float x[8];
    #pragma unroll
    for (int i = 0; i < 8; ++i)
        x[i] = TR ? W[(size_t)(k + i) * ldw + n] : W[(size_t)n * ldw + k + i];
    unsigned h[4], l[4];
    split2(x[0], x[1], h[0], l[0]);
    split2(x[2], x[3], h[1], l[1]);
    split2(x[4], x[5], h[2], l[2]);
    split2(x[6], x[7], h[3], l[3]);
    unsigned* base = out + (size_t)n * K + kt * 32;
    *(uint4*)(base + (((2 * j) ^ (n & 7)) * 4))     = make_uint4(h[0], h[1], h[2], h[3]);
    *(uint4*)(base + (((2 * j + 1) ^ (n & 7)) * 4)) = make_uint4(l[0], l[1], l[2], l[3]);
}

// ---------------------------------------------------------------------------
// Split-bf16 MFMA GEMM (unchanged; verified rounds 1-4).
// ---------------------------------------------------------------------------
template<int AMODE, bool BIAS>
__global__ __launch_bounds__(256) void gemm_mfma(
    const float* __restrict__ A, const float* __restrict__ A2,
    const unsigned* __restrict__ Bp, const float* __restrict__ bias,
    float* __restrict__ C, int M, int N, int K, int lda, int ldc)
{
    __shared__ uint4 Ab[1024];
    __shared__ uint4 Bb[1024];
    int tid = threadIdx.x;
    int lane = tid & 63, wid = tid >> 6;
    int wr = wid >> 1, wc = wid & 1;
    int n0 = blockIdx.x * 128, m0 = blockIdx.y * 128;
    int r15 = lane & 15, s = lane >> 4;

    f32x4 acc[4][4];
    #pragma unroll
    for (int i = 0; i < 4; ++i)
        #pragma unroll
        for (int j = 0; j < 4; ++j) acc[i][j] = 0.0f;

    for (int kt = 0; kt < (K >> 5); ++kt) {
        int k0 = kt * 32;
        #pragma unroll
        for (int q = 0; q < 2; ++q) {
            int idx = q * 256 + tid;
            int row = idx >> 2, j = idx & 3;
            const float* ap;
            if (AMODE == 1) {
                int gm = m0 + row;
                ap = (gm < 4096) ? (A + (size_t)gm * lda) : (A2 + (size_t)(gm - 4096) * lda);
            } else {
                ap = A + (size_t)(m0 + row) * lda;
            }
            float4 x0 = *(const float4*)(ap + k0 + j * 8);
            float4 x1 = *(const float4*)(ap + k0 + j * 8 + 4);
            unsigned h[4], l[4];
            split2(x0.x, x0.y, h[0], l[0]);
            split2(x0.z, x0.w, h[1], l[1]);
            split2(x1.x, x1.y, h[2], l[2]);
            split2(x1.z, x1.w, h[3], l[3]);
            Ab[row * 8 + (((2 * j) ^ (row & 7)))]     = make_uint4(h[0], h[1], h[2], h[3]);
            Ab[row * 8 + (((2 * j + 1) ^ (row & 7)))] = make_uint4(l[0], l[1], l[2], l[3]);
        }
        #pragma unroll
        for (int q = 0; q < 4; ++q) {
            int idx = q * 256 + tid;
            int row = idx >> 3, slot = idx & 7;
            Bb[idx] = *(const uint4*)(Bp + (size_t)(n0 + row) * K + k0 + slot * 4);
        }
        __syncthreads();
        FragU ahi[4], alo[4], bhi[4], blo[4];
        #pragma unroll
        for (int f = 0; f < 4; ++f) {
            int ar = wr * 64 + f * 16 + r15;
            ahi[f].u = Ab[ar * 8 + ((2 * s) ^ (ar & 7))];
            alo[f].u = Ab[ar * 8 + ((2 * s + 1) ^ (ar & 7))];
            int br = wc * 64 + f * 16 + r15;
            bhi[f].u = Bb[br * 8 + ((2 * s) ^ (br & 7))];
            blo[f].u = Bb[br * 8 + ((2 * s + 1) ^ (br & 7))];
        }
        #pragma unroll
        for (int fi = 0; fi < 4; ++fi)
            #pragma unroll
            for (int fj = 0; fj < 4; ++fj) {
                acc[fi][fj] = __builtin_amdgcn_mfma_f32_16x16x32_bf16(ahi[fi].h, bhi[fj].h, acc[fi][fj], 0, 0, 0);
                acc[fi][fj] = __builtin_amdgcn_mfma_f32_16x16x32_bf16(ahi[fi].h, blo[fj].h, acc[fi][fj], 0, 0, 0);
                acc[fi][fj] = __builtin_amdgcn_mfma_f32_16x16x32_bf16(alo[fi].h, bhi[fj].h, acc[fi][fj], 0, 0, 0);
            }
        __syncthreads();
    }
    int r4 = (lane >> 4) * 4;
    #pragma unroll
    for (int fj = 0; fj < 4; ++fj) {
        int n = n0 + wc * 64 + fj * 16 + r15;
        float bv = BIAS ? bias[n] : 0.f;
        #pragma unroll
        for (int fi = 0; fi < 4; ++fi) {
            int m = m0 + wr * 64 + fi * 16 + r4;
            #pragma unroll
            for (int r = 0; r < 4; ++r)
                C[(size_t)(m + r) * ldc + n] = acc[fi][fj][r] + bv;
        }
    }
}

// ---------------------------------------------------------------------------
// Fused TXL attention (unchanged, fp32).
// ---------------------------------------------------------------------------
__global__ __launch_bounds__(256) void attn_fused(
    const float* __restrict__ qkv, const float* __restrict__ rk,
    const float* __restrict__ u_, const float* __restrict__ v_,
    float* __restrict__ y1)
{
    __shared__ float qu[64][68], qv[64][68], Kt[64][68], Vt[64][68];
    __shared__ float RKs[128][68];
    __shared__ float S[64][68];
    __shared__ float mrow[64], lrow[64], scalef[64];
    __shared__ float pmax[64][16], psum[64][16];

    int tid = threadIdx.x;
    int it = blockIdx.x, b = blockIdx.y, h = blockIdx.z;
    int i0 = it * 64;
    int ti = tid >> 4, tj = tid & 15;

    {
        int r = tid >> 2, c0 = (tid & 3) * 16;
        size_t base = ((size_t)(i0 + r + 512) * 8 + b) * 3072 + h * 64;
        #pragma unroll
        for (int q = 0; q < 4; ++q) {
            int c = c0 + q * 4;
            float4 qq = *(const float4*)&qkv[base + c];
            float4 uu = *(const float4*)&u_[h * 64 + c];
            float4 vv = *(const float4*)&v_[h * 64 + c];
            *(float4*)&qu[r][c] = make_float4(qq.x + uu.x, qq.y + uu.y, qq.z + uu.z, qq.w + uu.w);
            *(float4*)&qv[r][c] = make_float4(qq.x + vv.x, qq.y + vv.y, qq.z + vv.z, qq.w + vv.w);
        }
    }
    if (tid < 64) { mrow[tid] = -1e30f; lrow[tid] = 0.f; }

    float Od[4][4] = {};
    int njt = it + 9;

    for (int jt = 0; jt < njt; ++jt) {
        int j0 = jt * 64;
        __syncthreads();
        {
            int r = tid >> 2, c0 = (tid & 3) * 16;
            size_t kb = ((size_t)(j0 + r) * 8 + b) * 3072 + 1024 + h * 64;
            #pragma unroll
            for (int q = 0; q < 4; ++q) {
                int c = c0 + q * 4;
                *(float4*)&Kt[r][c] = *(const float4*)&qkv[kb + c];
                *(float4*)&Vt[r][c] = *(const float4*)&qkv[kb + 1024 + c];
            }
        }
        {
            int r2 = tid >> 1, c0 = (tid & 1) * 32;
            int jj = j0 - i0 + 448 + r2;
            jj = jj < 0 ? 0 : (jj > 1023 ? 1023 : jj);
            size_t rb = (size_t)jj * 1024 + h * 64;
            #pragma unroll
            for (int q = 0; q < 8; ++q) {
                int c = c0 + q * 4;
                *(float4*)&RKs[r2][c] = *(const float4*)&rk[rb + c];
            }
        }
        __syncthreads();

        float acc[4][4] = {};
        int jlb = (tj - ti) * 4 + 60;
        #pragma unroll 4
        for (int d4 = 0; d4 < 64; d4 += 4) {
            float4 Aq[4], Cq[4], Kv[4], Rv[7];
            #pragma unroll
            for (int i = 0; i < 4; ++i) {
                Aq[i] = *(float4*)&qu[ti * 4 + i][d4];
                Cq[i] = *(float4*)&qv[ti * 4 + i][d4];
                Kv[i] = *(float4*)&Kt[tj * 4 + i][d4];
            }
            #pragma unroll
            for (int t = 0; t < 7; ++t)
                Rv[t] = *(float4*)&RKs[jlb + t][d4];
            #pragma unroll
            for (int i = 0; i < 4; ++i)
                #pragma unroll
                for (int j = 0; j < 4; ++j) {
                    float4 kk = Kv[j];
                    float4 rr = Rv[j - i + 3];
                    acc[i][j] += Aq[i].x * kk.x + Aq[i].y * kk.y + Aq[i].z * kk.z + Aq[i].w * kk.w
                               + Cq[i].x * rr.x + Cq[i].y * rr.y + Cq[i].z * rr.z + Cq[i].w * rr.w;
                }
        }
        #pragma unroll
        for (int i = 0; i < 4; ++i) {
            int gi = i0 + ti * 4 + i;
            float mx = -1e30f;
            #pragma unroll
            for (int j = 0; j < 4; ++j) {
                int gj = j0 + tj * 4 + j;
                float vS = acc[i][j] * 0.125f;
                if (gj > gi + 512) vS = -1e30f;
                acc[i][j] = vS;
                mx = fmaxf(mx, vS);
            }
            pmax[ti * 4 + i][tj] = mx;
        }
        __syncthreads();
        if (tid < 64) {
            float mo = mrow[tid], mn = mo;
            #pragma unroll
            for (int t = 0; t < 16; ++t) mn = fmaxf(mn, pmax[tid][t]);
            mrow[tid] = mn;
            scalef[tid] = __expf(mo - mn);
        }
        __syncthreads();
        #pragma unroll
        for (int i = 0; i < 4; ++i) {
            int ri = ti * 4 + i;
            float mn = mrow[ri];
            float4 pv;
            pv.x = __expf(acc[i][0] - mn);
            pv.y = __expf(acc[i][1] - mn);
            pv.z = __expf(acc[i][2] - mn);
            pv.w = __expf(acc[i][3] - mn);
            *(float4*)&S[ri][tj * 4] = pv;
            psum[ri][tj] = pv.x + pv.y + pv.z + pv.w;
            float scl = scalef[ri];
            #pragma unroll
            for (int j2 = 0; j2 < 4; ++j2) Od[i][j2] *= scl;
        }
        __syncthreads();
        if (tid < 64) {
            float s = 0.f;
            #pragma unroll
            for (int t = 0; t < 16; ++t) s += psum[tid][t];
            lrow[tid] = lrow[tid] * scalef[tid] + s;
        }
        #pragma unroll 4
        for (int jb = 0; jb < 64; jb += 4) {
            float4 p0 = *(float4*)&S[ti * 4 + 0][jb];
            float4 p1 = *(float4*)&S[ti * 4 + 1][jb];
            float4 p2 = *(float4*)&S[ti * 4 + 2][jb];
            float4 p3 = *(float4*)&S[ti * 4 + 3][jb];
            float4 v0 = *(float4*)&Vt[jb + 0][tj * 4];
            float4 v1 = *(float4*)&Vt[jb + 1][tj * 4];
            float4 v2 = *(float4*)&Vt[jb + 2][tj * 4];
            float4 v3 = *(float4*)&Vt[jb + 3][tj * 4];
            float4 pr[4] = {p0, p1, p2, p3};
            #pragma unroll
            for (int i = 0; i < 4; ++i) {
                Od[i][0] += pr[i].x * v0.x + pr[i].y * v1.x + pr[i].z * v2.x + pr[i].w * v3.x;
                Od[i][1] += pr[i].x * v0.y + pr[i].y * v1.y + pr[i].z * v2.y + pr[i].w * v3.y;
                Od[i][2] += pr[i].x * v0.z + pr[i].y * v1.z + pr[i].z * v2.z + pr[i].w * v3.z;
                Od[i][3] += pr[i].x * v0.w + pr[i].y * v1.w + pr[i].z * v2.w + pr[i].w * v3.w;
            }
        }
    }
    __syncthreads();
    #pragma unroll
    for (int i = 0; i < 4; ++i) {
        int ri = ti * 4 + i;
        float inv = 1.f / lrow[ri];
        float4 o = make_float4(Od[i][0] * inv, Od[i][1] * inv, Od[i][2] * inv, Od[i][3] * inv);
        *(float4*)&y1[((size_t)(i0 + ri) * 8 + b) * 1024 + h * 64 + tj * 4] = o;
    }
}

// ---------------------------------------------------------------------------
// Whh -> MFMA A-fragments, per-block contiguous:
// WhhG[((g64*32 + kt)*3 + gate)*2 + plane][lane] (uint4). Block g64 reads a
// linear 192 KB run -> global_load_lds staging is a plain async copy.
// ---------------------------------------------------------------------------
__global__ __launch_bounds__(256) void prep_whh(
    const float* __restrict__ Whh, uint4* __restrict__ outp)
{
    int idx = blockIdx.x * 256 + threadIdx.x;   // 64*32*3*64 = 393216
    if (idx >= 393216) return;
    int lane = idx & 63;
    int rest = idx >> 6;            // ((g64*32 + kt)*3 + gate)
    int gate = rest % 3;
    int kt   = (rest / 3) & 31;
    int g64  = rest / 96;
    int n = gate * 1024 + g64 * 16 + (lane & 15);
    int k = kt * 32 + (lane >> 4) * 8;
    const float* src = Whh + (size_t)n * 1024 + k;
    float4 x0 = *(const float4*)src, x1 = *(const float4*)(src + 4);
    unsigned h[4], l[4];
    split2(x0.x, x0.y, h[0], l[0]);
    split2(x0.z, x0.w, h[1], l[1]);
    split2(x1.x, x1.y, h[2], l[2]);
    split2(x1.z, x1.w, h[3], l[3]);
    outp[((size_t)rest * 2 + 0) * 64 + lane] = make_uint4(h[0], h[1], h[2], h[3]);
    outp[((size_t)rest * 2 + 1) * 64 + lane] = make_uint4(l[0], l[1], l[2], l[3]);
}

// ---------------------------------------------------------------------------
// One GRU step via MFMA, Whh staged through LDS with global_load_lds (dbuf).
// 64 blocks x 256 threads (4 waves; waves 0-2 compute gates r/z/n, wave 3
// stages only). 8 chunks of 4 kt (24 KB); 2-phase pipeline:
//   STAGE(c+1) -> compute(c) -> __syncthreads (vmcnt(0) drain = chunk c+1 ready)
// LDS: Bf 64KB + Wst 2x24KB + red 3KB = 115KB -> 1 block/CU.
// ---------------------------------------------------------------------------
__global__ __launch_bounds__(256) void gru_step_mfma(
    const float* __restrict__ hin, float* __restrict__ hout,
    const uint4* __restrict__ WhhG, const float* __restrict__ bhh,
    const float* __restrict__ xg, float* __restrict__ out, int t)
{
    __shared__ uint4 Bf[4096];        // h frags: [kt32][plane2][lane64]
    __shared__ uint4 Wst[2][1536];    // staged Whh: [ktL4][gate3][plane2][lane64]
    __shared__ float red[3][64][4];
    int tid = threadIdx.x;
    int lane = tid & 63, wv = tid >> 6;
    int g64 = blockIdx.x;

    // epilogue operand prefetch (independent)
    int col = lane & 15;
    int d0 = g64 * 16 + (lane >> 4) * 4;
    bool act = (wv == 0) && (col < 8);
    float4 xr4, xz4, xn4, hp4, br4, bz4, bn4;
    if (act) {
        size_t xb = ((size_t)t * 8 + col) * 3072 + d0;
        xr4 = *(const float4*)&xg[xb];
        xz4 = *(const float4*)&xg[xb + 1024];
        xn4 = *(const float4*)&xg[xb + 2048];
        hp4 = *(const float4*)&hin[col * 1024 + d0];
        br4 = *(const float4*)&bhh[d0];
        bz4 = *(const float4*)&bhh[1024 + d0];
        bn4 = *(const float4*)&bhh[2048 + d0];
    }

    // build B (h) split-bf16 fragments: 1024 slots / 256 threads = 4 iters
    for (int s = tid; s < 1024; s += 256) {
        int b = s & 7, oct = (s >> 3) & 3, kt = s >> 5;
        const float* hp = hin + b * 1024 + kt * 32 + oct * 8;
        float4 x0 = *(const float4*)hp, x1 = *(const float4*)(hp + 4);
        unsigned hh[4], ll[4];
        split2(x0.x, x0.y, hh[0], ll[0]);
        split2(x0.z, x0.w, hh[1], ll[1]);
        split2(x1.x, x1.y, hh[2], ll[2]);
        split2(x1.z, x1.w, hh[3], ll[3]);
        int ln = oct * 16 + b;
        Bf[(kt * 2 + 0) * 64 + ln] = make_uint4(hh[0], hh[1], hh[2], hh[3]);
        Bf[(kt * 2 + 1) * 64 + ln] = make_uint4(ll[0], ll[1], ll[2], ll[3]);
    }

    const uint4* wbase = WhhG + (size_t)g64 * 12288;

    // stage chunk 0 (6 async 1KB-per-wave copies each wave)
    #pragma unroll
    for (int i = 0; i < 6; ++i) {
        int slot = (i * 4 + wv) * 64;
        gl_lds16(wbase + slot + lane, &Wst[0][slot]);
    }
    __syncthreads();   // drains vmcnt(0): chunk0 + h loads; lgkmcnt: Bf writes

    f32x4 acc = 0.0f;
    for (int c = 0; c < 8; ++c) {
        if (c < 7) {
            const uint4* src = wbase + (c + 1) * 1536;
            uint4* dst = &Wst[(c + 1) & 1][0];
            #pragma unroll
            for (int i = 0; i < 6; ++i) {
                int slot = (i * 4 + wv) * 64;
                gl_lds16(src + slot + lane, dst + slot);
            }
        }
        if (wv < 3) {
            const uint4* Wc = &Wst[c & 1][0];
            #pragma unroll
            for (int ktL = 0; ktL < 4; ++ktL) {
                int kt = c * 4 + ktL;
                FragU ah, al, bh, bl;
                ah.u = Wc[((ktL * 3 + wv) * 2 + 0) * 64 + lane];
                al.u = Wc[((ktL * 3 + wv) * 2 + 1) * 64 + lane];
                bh.u = Bf[(kt * 2 + 0) * 64 + lane];
                bl.u = Bf[(kt * 2 + 1) * 64 + lane];
                acc = __builtin_amdgcn_mfma_f32_16x16x32_bf16(ah.h, bh.h, acc, 0, 0, 0);
                acc = __builtin_amdgcn_mfma_f32_16x16x32_bf16(ah.h, bl.h, acc, 0, 0, 0);
                acc = __builtin_amdgcn_mfma_f32_16x16x32_bf16(al.h, bh.h, acc, 0, 0, 0);
            }
        }
        __syncthreads();   // vmcnt(0): chunk c+1 landed; also guards buf reuse
    }
    if (wv < 3) *(f32x4*)&red[wv][lane][0] = acc;
    __syncthreads();

    if (act) {
        f32x4 aR = *(f32x4*)&red[0][lane][0];
        f32x4 aZ = *(f32x4*)&red[1][lane][0];
        f32x4 aN = *(f32x4*)&red[2][lane][0];
        float xr[4] = {xr4.x, xr4.y, xr4.z, xr4.w};
        float xz[4] = {xz4.x, xz4.y, xz4.z, xz4.w};
        float xn[4] = {xn4.x, xn4.y, xn4.z, xn4.w};
        float hp[4] = {hp4.x, hp4.y, hp4.z, hp4.w};
        float br[4] = {br4.x, br4.y, br4.z, br4.w};
        float bz[4] = {bz4.x, bz4.y, bz4.z, bz4.w};
        float bn[4] = {bn4.x, bn4.y, bn4.z, bn4.w};
        float hn[4];
        #pragma unroll
        for (int r = 0; r < 4; ++r) {
            float rr = 1.f / (1.f + __expf(-(xr[r] + aR[r] + br[r])));
            float zz = 1.f / (1.f + __expf(-(xz[r] + aZ[r] + bz[r])));
            float nn = tanhf(xn[r] + rr * (aN[r] + bn[r]));
            hn[r] = (1.f - zz) * nn + zz * hp[r];
        }
        float4 hv = make_float4(hn[0], hn[1], hn[2], hn[3]);
        *(float4*)&hout[col * 1024 + d0] = hv;
        *(float4*)&out[((size_t)t * 8 + col) * 1024 + d0] = hv;
    }
}

// ---------------------------------------------------------------------------
extern "C" void kernel_launch(void* const* d_in, const int* in_sizes, int n_in,
                              void* d_out, int out_size, void* d_ws, size_t ws_size,
                              hipStream_t stream) {
    (void)in_sizes; (void)n_in; (void)out_size; (void)ws_size;
    const float* inputs = (const float*)d_in[0];
    const float* r_in   = (const float*)d_in[1];
    const float* u_in   = (const float*)d_in[2];
    const float* v_in   = (const float*)d_in[3];
    const float* mem    = (const float*)d_in[4];
    const float* Wqkv   = (const float*)d_in[5];
    const float* Wr     = (const float*)d_in[6];
    const float* Wo     = (const float*)d_in[7];
    const float* Wih    = (const float*)d_in[8];
    const float* Whh    = (const float*)d_in[9];
    const float* bih    = (const float*)d_in[10];
    const float* bhh    = (const float*)d_in[11];
    const float* h0     = (const float*)d_in[12];
    float* out = (float*)d_out;
    float* ws = (float*)d_ws;

    float*    qkv   = ws;                       // 25165824 (dead after attn; reused for WhhG)
    float*    rk    = ws + 25165824;            //  1048576
    float*    y1    = ws + 26214400;            //  4194304
    float*    y2    = ws + 30408704;            //  4194304
    float*    xg    = ws + 34603008;            // 12582912
    float*    hA    = ws + 47185920;            //     8192
    float*    hB    = ws + 47194112;            //     8192
    unsigned* WqkvP = (unsigned*)(ws + 47202304);   // 3145728
    unsigned* WrP   = (unsigned*)(ws + 50348032);   // 1048576
    unsigned* WoP   = (unsigned*)(ws + 51396608);   // 1048576
    unsigned* WihP  = (unsigned*)(ws + 52445184);   // 3145728
    uint4*    WhhG  = (uint4*)qkv;                  // 786432 uint4 = 12.6 MB

    dim3 blk(256);
    // ---- weight prep (GEMM layouts)
    prep_w<true ><<<1536, blk, 0, stream>>>(Wqkv, WqkvP, 3072, 1024, 3072);
    prep_w<true ><<< 512, blk, 0, stream>>>(Wr,   WrP,   1024, 1024, 1024);
    prep_w<true ><<< 512, blk, 0, stream>>>(Wo,   WoP,   1024, 1024, 1024);
    prep_w<false><<<1536, blk, 0, stream>>>(Wih,  WihP,  3072, 1024, 1024);

    // ---- qkv = [mem; inputs] @ W_qkv   (8192 x 3072, K=1024)
    gemm_mfma<1, false><<<dim3(24, 64), blk, 0, stream>>>(
        mem, inputs, WqkvP, nullptr, qkv, 8192, 3072, 1024, 1024, 3072);
    // ---- rk = r @ W_r                  (1024 x 1024)
    gemm_mfma<0, false><<<dim3(8, 8), blk, 0, stream>>>(
        r_in, nullptr, WrP, nullptr, rk, 1024, 1024, 1024, 1024, 1024);
    // ---- fused attention -> y1
    attn_fused<<<dim3(8, 8, 16), blk, 0, stream>>>(qkv, rk, u_in, v_in, y1);
    // ---- Whh fragment prep (into dead qkv space; after attn in-stream)
    prep_whh<<<1536, blk, 0, stream>>>(Whh, WhhG);
    // ---- y2 = y1 @ W_o                 (4096 x 1024)
    gemm_mfma<0, false><<<dim3(8, 32), blk, 0, stream>>>(
        y1, nullptr, WoP, nullptr, y2, 4096, 1024, 1024, 1024, 1024);
    // ---- xg = y2 @ W_ih^T + b_ih       (4096 x 3072)
    gemm_mfma<0, true><<<dim3(24, 32), blk, 0, stream>>>(
        y2, nullptr, WihP, bih, xg, 4096, 3072, 1024, 1024, 3072);

    // ---- GRU recurrence: 512 lean MFMA step-kernels (staged Whh)
    const float* hin = h0;
    for (int s = 0; s < 512; ++s) {
        float* hp = (s & 1) ? hB : hA;
        gru_step_mfma<<<64, blk, 0, stream>>>(hin, hp, WhhG, bhh, xg, out, s);
        hin = hp;
    }
}